// Round 10
// baseline (65.355 us; speedup 1.0000x reference)
//
#include <hip/hip_runtime.h>
#include <math.h>

#define EPSF 1e-6f

constexpr int B_  = 2;
constexpr int L_  = 1024;
constexpr int D_  = 512;
constexpr int H_  = 8;
constexpr int DH_ = 64;
constexpr int BL_ = B_ * L_;   // 2048
constexpr int BH_ = B_ * H_;   // 16
constexpr int CT_ = 64;        // chunk length
constexpr int NC_ = L_ / CT_;  // 16 chunks

typedef __attribute__((ext_vector_type(8))) short bf16x8;
typedef __attribute__((ext_vector_type(4))) float f32x4;

__device__ __forceinline__ unsigned short f2bf(float f) {
  union { float f; unsigned int u; } v; v.f = f;
  const unsigned int u = v.u;
  return (unsigned short)((u + 0x7FFFu + ((u >> 16) & 1u)) >> 16);  // RNE
}
__device__ __forceinline__ float bf2f(unsigned short u) {
  union { unsigned int u; float f; } v; v.u = ((unsigned int)u) << 16;
  return v.f;
}

// Swizzled ushort index for a [64][64] bf16 LDS tile: conflict-free b128 reads.
__device__ __forceinline__ int sw(int row, int col) {
  return row * 64 + (col ^ ((row & 7) << 3));
}

// ---------------------------------------------------------------------------
// Weight prep: WT[z][n][k] = bf16(W[z][k][n]) for z in {Wq,Wk,Wv,Wo}.
// LDS-tiled transpose, 64x64 tiles, grid (8,8,4).
// ---------------------------------------------------------------------------
__global__ __launch_bounds__(256) void convw_k(const float* __restrict__ Wq,
                                               const float* __restrict__ Wk,
                                               const float* __restrict__ Wv,
                                               const float* __restrict__ Wo,
                                               unsigned short* __restrict__ WT) {
  const int z = blockIdx.z;
  const float* W = (z == 0) ? Wq : (z == 1) ? Wk : (z == 2) ? Wv : Wo;
  unsigned short* O = WT + (size_t)z * D_ * D_;
  __shared__ float t[64][65];
  const int tid = threadIdx.x;
  const int k0 = blockIdx.x * 64, n0 = blockIdx.y * 64;
#pragma unroll
  for (int it = 0; it < 16; ++it) {
    const int idx = it * 256 + tid;
    const int r = idx >> 6, c = idx & 63;
    t[r][c] = W[(size_t)(k0 + r) * D_ + n0 + c];
  }
  __syncthreads();
#pragma unroll
  for (int it = 0; it < 16; ++it) {
    const int idx = it * 256 + tid;
    const int r = idx >> 6, c = idx & 63;
    O[(size_t)(n0 + r) * D_ + k0 + c] = f2bf(t[c][r]);
  }
}

// ---------------------------------------------------------------------------
// Fused projection GEMMs, 64x64 tile, 768 blocks = 3/CU (z = 0:Q, 1:K, 2:V):
// out = sigmoid?(A @ W + b) stored BF16 permuted to [B,H,L,Dh]; z<2 also
// writes per-(chunk,head) column sums of the ROUNDED values. B operand comes
// pre-transposed bf16 [n][k] -> contiguous staging, zero conversions.
// ---------------------------------------------------------------------------
__global__ __launch_bounds__(256) void proj3_k(const float* __restrict__ Qin,
                                               const float* __restrict__ Kin,
                                               const float* __restrict__ Vin,
                                               const unsigned short* __restrict__ WT,
                                               const float* __restrict__ bq,
                                               const float* __restrict__ bk,
                                               const float* __restrict__ bv,
                                               unsigned short* __restrict__ Qb,
                                               unsigned short* __restrict__ Kb,
                                               unsigned short* __restrict__ Vb,
                                               float* __restrict__ sumQ,
                                               float* __restrict__ sumK) {
  const int z = blockIdx.z;
  const float* A    = (z == 0) ? Qin : (z == 1) ? Kin : Vin;
  const unsigned short* Wt = WT + (size_t)z * D_ * D_;
  const float* bias = (z == 0) ? bq  : (z == 1) ? bk  : bv;
  unsigned short* out = (z == 0) ? Qb : (z == 1) ? Kb : Vb;
  float* csum       = (z == 0) ? sumQ : (z == 1) ? sumK : nullptr;
  const bool sig = (z < 2);

  __shared__ __align__(16) short Als[64 * 40];
  __shared__ __align__(16) short Bls[64 * 40];
  const int tid = threadIdx.x;
  const int m0 = blockIdx.x * 64, n0 = blockIdx.y * 64;
  const int arow = tid >> 2, akq = (tid & 3) << 3;  // shared by A and B staging
  const int lane = tid & 63, wid = tid >> 6;
  const int wr = wid >> 1, wc = wid & 1;
  const int lrow = lane & 15, lk = (lane >> 4) << 3;

  f32x4 acc[2][2] = {{{0.f, 0.f, 0.f, 0.f}, {0.f, 0.f, 0.f, 0.f}},
                     {{0.f, 0.f, 0.f, 0.f}, {0.f, 0.f, 0.f, 0.f}}};
  float ra[8];
  bf16x8 pb;

  auto loadAB = [&](int kt) {
    const float4 f0 = *(const float4*)&A[(size_t)(m0 + arow) * D_ + kt + akq];
    const float4 f1 = *(const float4*)&A[(size_t)(m0 + arow) * D_ + kt + akq + 4];
    ra[0] = f0.x; ra[1] = f0.y; ra[2] = f0.z; ra[3] = f0.w;
    ra[4] = f1.x; ra[5] = f1.y; ra[6] = f1.z; ra[7] = f1.w;
    pb = *(const bf16x8*)&Wt[(size_t)(n0 + arow) * D_ + kt + akq];
  };
  auto writeLDS = [&]() {
    bf16x8 pa;
#pragma unroll
    for (int j = 0; j < 8; ++j) pa[j] = (short)f2bf(ra[j]);
    *(bf16x8*)&Als[arow * 40 + akq] = pa;
    *(bf16x8*)&Bls[arow * 40 + akq] = pb;
  };
  auto compute = [&]() {
    bf16x8 a0 = *(const bf16x8*)&Als[(wr * 32 + lrow) * 40 + lk];
    bf16x8 a1 = *(const bf16x8*)&Als[(wr * 32 + 16 + lrow) * 40 + lk];
    bf16x8 b0 = *(const bf16x8*)&Bls[(wc * 32 + lrow) * 40 + lk];
    bf16x8 b1 = *(const bf16x8*)&Bls[(wc * 32 + 16 + lrow) * 40 + lk];
    acc[0][0] = __builtin_amdgcn_mfma_f32_16x16x32_bf16(a0, b0, acc[0][0], 0, 0, 0);
    acc[0][1] = __builtin_amdgcn_mfma_f32_16x16x32_bf16(a0, b1, acc[0][1], 0, 0, 0);
    acc[1][0] = __builtin_amdgcn_mfma_f32_16x16x32_bf16(a1, b0, acc[1][0], 0, 0, 0);
    acc[1][1] = __builtin_amdgcn_mfma_f32_16x16x32_bf16(a1, b1, acc[1][1], 0, 0, 0);
  };

  loadAB(0);
  writeLDS();
  for (int kt = 32; kt < D_; kt += 32) {
    loadAB(kt);
    __syncthreads();
    compute();
    __syncthreads();
    writeLDS();
  }
  __syncthreads();
  compute();

  const int b = m0 >> 10, h = n0 >> 6;
  float psum[2] = {0.f, 0.f};
#pragma unroll
  for (int j = 0; j < 2; ++j) {
    const int col = n0 + wc * 32 + j * 16 + lrow;
    const float bv4 = bias[col];
    const int dh = col & 63;
#pragma unroll
    for (int i = 0; i < 2; ++i) {
#pragma unroll
      for (int r = 0; r < 4; ++r) {
        const int row = m0 + wr * 32 + i * 16 + (lane >> 4) * 4 + r;
        float x = acc[i][j][r] + bv4;
        if (sig) x = 1.0f / (1.0f + expf(-x));
        const unsigned short ub = f2bf(x);
        const int l = row & (L_ - 1);
        out[(((size_t)(b * H_ + h)) * L_ + l) * DH_ + dh] = ub;
        psum[j] += bf2f(ub);  // sum the ROUNDED value: exact decomposition
      }
    }
  }
  if (csum) {
    float* sumS = (float*)Als;
#pragma unroll
    for (int j = 0; j < 2; ++j) {
      psum[j] += __shfl_xor(psum[j], 16);
      psum[j] += __shfl_xor(psum[j], 32);
      if ((lane >> 4) == 0) sumS[wr * 64 + wc * 32 + j * 16 + lrow] = psum[j];
    }
    __syncthreads();
    if (tid < 64) {
      const int c = (m0 & (L_ - 1)) >> 6;
      const int bc = (b * H_ + h) * NC_ + c;
      csum[bc * DH_ + tid] = sumS[tid] + sumS[64 + tid];
    }
  }
}

// ---------------------------------------------------------------------------
// Flow phase 1: 256 thr, 4-wave d-split scans. bf16 q/k in, fp32 LDS/scans.
// ---------------------------------------------------------------------------
__global__ __launch_bounds__(256) void flow_phase1_k(const unsigned short* __restrict__ Qb,
                                                     const unsigned short* __restrict__ Kb,
                                                     const float* __restrict__ sumQ,
                                                     const float* __restrict__ sumK,
                                                     float* __restrict__ qscale,
                                                     float* __restrict__ si_a,
                                                     float* __restrict__ so_a,
                                                     float* __restrict__ sumQSI,
                                                     float* __restrict__ sumKSO) {
  const int bc = blockIdx.x, bh = bc >> 4, c = bc & (NC_ - 1);
  const int g = bc * CT_;
  const int tid = threadIdx.x, lane = tid & 63, w = tid >> 6;
  __shared__ float qS[64][65], kS[64][65];
  __shared__ float pqS[64], pkS[64];
  __shared__ float aS[4][64], bS[4][64];
  __shared__ float siS[64], soS[64];
#pragma unroll
  for (int it = 0; it < 2; ++it) {
    const int i8 = it * 256 + tid;
    const int row = i8 >> 3, d0 = (i8 & 7) << 3;
    const bf16x8 qv = *(const bf16x8*)&Qb[(size_t)g * DH_ + i8 * 8];
    const bf16x8 kv = *(const bf16x8*)&Kb[(size_t)g * DH_ + i8 * 8];
#pragma unroll
    for (int j = 0; j < 8; ++j) {
      qS[row][d0 + j] = bf2f((unsigned short)qv[j]);
      kS[row][d0 + j] = bf2f((unsigned short)kv[j]);
    }
  }
  if (tid < 64) {
    float pq = 0.f, pk = 0.f;
    for (int cc = 0; cc < c; ++cc) {
      pq += sumQ[(bh * NC_ + cc) * DH_ + tid];
      pk += sumK[(bh * NC_ + cc) * DH_ + tid];
    }
    pqS[tid] = pq; pkS[tid] = pk;
  }
  __syncthreads();
  float ap = 0.f, bp = 0.f;
  for (int dd = 0; dd < 16; ++dd) {
    const int d = w * 16 + dd;
    const float qv = qS[lane][d];
    const float kv = kS[lane][d];
    float ck = kv, cq = qv;
#pragma unroll
    for (int off = 1; off < 64; off <<= 1) {
      const float t1 = __shfl_up(ck, off);
      const float t2 = __shfl_up(cq, off);
      ck += (lane >= off) ? t1 : 0.f;
      cq += (lane >= off) ? t2 : 0.f;
    }
    ck += pkS[d];
    cq += pqS[d];
    ap += (qv + EPSF) * (ck + EPSF);
    bp += (kv + EPSF) * (cq + EPSF);
  }
  aS[w][lane] = ap; bS[w][lane] = bp;
  __syncthreads();
  const float normal = (float)(c * CT_ + lane + 1);
  if (w == 0) {
    const float a = aS[0][lane] + aS[1][lane] + aS[2][lane] + aS[3][lane];
    const float b = bS[0][lane] + bS[1][lane] + bS[2][lane] + bS[3][lane];
    const float si = normal / a, so = normal / b;
    qscale[g + lane] = 1.0f / a;
    si_a[g + lane] = si;
    so_a[g + lane] = so;
    siS[lane] = si; soS[lane] = so;
  }
  __syncthreads();
  float sq = 0.f, sk = 0.f;
#pragma unroll
  for (int li = 0; li < 16; ++li) {
    const int l = w * 16 + li;
    sq += qS[l][lane] * siS[l];
    sk += kS[l][lane] * soS[l];
  }
  aS[w][lane] = sq; bS[w][lane] = sk;
  __syncthreads();
  if (tid < 64) {
    sumQSI[bc * DH_ + tid] = aS[0][tid] + aS[1][tid] + aS[2][tid] + aS[3][tid];
    sumKSO[bc * DH_ + tid] = bS[0][tid] + bS[1][tid] + bS[2][tid] + bS[3][tid];
  }
}

// ---------------------------------------------------------------------------
// Flow phase 2: 256 thr, 4-wave d-split. Outputs salloc, e, chunk sumE.
// ---------------------------------------------------------------------------
__global__ __launch_bounds__(256) void flow_phase2_k(const unsigned short* __restrict__ Qb,
                                                     const unsigned short* __restrict__ Kb,
                                                     const float* __restrict__ sumQSI,
                                                     const float* __restrict__ sumKSO,
                                                     const float* __restrict__ si_a,
                                                     const float* __restrict__ so_a,
                                                     float* __restrict__ salloc,
                                                     float* __restrict__ e_a,
                                                     float* __restrict__ sumE) {
  const int bc = blockIdx.x, bh = bc >> 4, c = bc & (NC_ - 1);
  const int g = bc * CT_;
  const int tid = threadIdx.x, lane = tid & 63, w = tid >> 6;
  __shared__ float qS[64][65], kS[64][65];
  __shared__ float pqS[64], pkS[64];
  __shared__ float aS[4][64], bS[4][64];
#pragma unroll
  for (int it = 0; it < 2; ++it) {
    const int i8 = it * 256 + tid;
    const int row = i8 >> 3, d0 = (i8 & 7) << 3;
    const bf16x8 qv = *(const bf16x8*)&Qb[(size_t)g * DH_ + i8 * 8];
    const bf16x8 kv = *(const bf16x8*)&Kb[(size_t)g * DH_ + i8 * 8];
#pragma unroll
    for (int j = 0; j < 8; ++j) {
      qS[row][d0 + j] = bf2f((unsigned short)qv[j]);
      kS[row][d0 + j] = bf2f((unsigned short)kv[j]);
    }
  }
  if (tid < 64) {
    float pq = 0.f, pk = 0.f;
    for (int cc = 0; cc < c; ++cc) {
      pq += sumQSI[(bh * NC_ + cc) * DH_ + tid];
      pk += sumKSO[(bh * NC_ + cc) * DH_ + tid];
    }
    pqS[tid] = pq; pkS[tid] = pk;
  }
  __syncthreads();
  const float si = si_a[g + lane];
  const float so = so_a[g + lane];
  float c1p = 0.f, c2p = 0.f;
  for (int dd = 0; dd < 16; ++dd) {
    const int d = w * 16 + dd;
    const float qv = qS[lane][d];
    const float kv = kS[lane][d];
    float ckso = kv * so, cqsi = qv * si;
#pragma unroll
    for (int off = 1; off < 64; off <<= 1) {
      const float t1 = __shfl_up(ckso, off);
      const float t2 = __shfl_up(cqsi, off);
      ckso += (lane >= off) ? t1 : 0.f;
      cqsi += (lane >= off) ? t2 : 0.f;
    }
    ckso += pkS[d];
    cqsi += pqS[d];
    c1p += (qv + EPSF) * (ckso + EPSF);
    c2p += (kv + EPSF) * (cqsi + EPSF);
  }
  aS[w][lane] = c1p; bS[w][lane] = c2p;
  __syncthreads();
  if (w == 0) {
    const float c1 = aS[0][lane] + aS[1][lane] + aS[2][lane] + aS[3][lane];
    const float c2 = bS[0][lane] + bS[1][lane] + bS[2][lane] + bS[3][lane];
    const float normal = (float)(c * CT_ + lane + 1);
    const float cs_sink = c1 / normal;
    salloc[g + lane] = 1.0f / (1.0f + expf(-cs_sink));
    float cs_src = c2 / normal;
    cs_src = fminf(1.0f, fmaxf(-1.0f, cs_src));
    const float e = expf(cs_src);
    e_a[g + lane] = e;
    float tot = e;
#pragma unroll
    for (int off = 32; off; off >>= 1) tot += __shfl_xor(tot, off);
    if (lane == 0) sumE[bc] = tot;
  }
}

// ---------------------------------------------------------------------------
// Fused: source_competition (inline prefix of sumE) + MFMA chunk-KV:
// KV[bc][d][m] = sum_l k[l,d] * (v[l,m]*comp[l])  ==  k^T @ v'.
// ---------------------------------------------------------------------------
__global__ __launch_bounds__(256) void flow_ckv_k(const unsigned short* __restrict__ K16,
                                                  const unsigned short* __restrict__ V16,
                                                  const float* __restrict__ e_a,
                                                  const float* __restrict__ sumE,
                                                  float* __restrict__ comp,
                                                  float* __restrict__ KV) {
  const int bc = blockIdx.x, bh = bc >> 4, c = bc & (NC_ - 1);
  const int g = bc * CT_;
  const int tid = threadIdx.x;
  __shared__ float compS[CT_];
  __shared__ __align__(16) unsigned short kT16[64 * 64];  // [d][l]
  __shared__ __align__(16) unsigned short vT16[64 * 64];  // [m][l] = v'[l][m]
  if (tid < 64) {
    const int lane = tid;
    const float e = e_a[g + lane];
    float se = (lane < c) ? sumE[bh * NC_ + lane] : 0.f;
#pragma unroll
    for (int off = 32; off; off >>= 1) se += __shfl_xor(se, off);
    float s = e;
#pragma unroll
    for (int off = 1; off < 64; off <<= 1) {
      const float t = __shfl_up(s, off);
      s += (lane >= off) ? t : 0.f;
    }
    const float cf = e / (se + s) * (float)(c * CT_ + lane + 1);
    compS[lane] = cf;
    comp[g + lane] = cf;
  }
  __syncthreads();
#pragma unroll
  for (int it = 0; it < 2; ++it) {
    const int i8 = it * 256 + tid;
    const int l = i8 >> 3, d0 = (i8 & 7) << 3;
    const bf16x8 kv = *(const bf16x8*)&K16[(size_t)g * DH_ + i8 * 8];
    const bf16x8 vv = *(const bf16x8*)&V16[(size_t)g * DH_ + i8 * 8];
    const float cl = compS[l];
#pragma unroll
    for (int j = 0; j < 8; ++j) {
      kT16[sw(d0 + j, l)] = (unsigned short)kv[j];
      vT16[sw(d0 + j, l)] = f2bf(bf2f((unsigned short)vv[j]) * cl);
    }
  }
  __syncthreads();
  const int lane = tid & 63, w = tid >> 6;
  const int fr = lane & 15, fk = (lane >> 4) << 3;
  f32x4 acc[4] = {{0.f, 0.f, 0.f, 0.f}, {0.f, 0.f, 0.f, 0.f},
                  {0.f, 0.f, 0.f, 0.f}, {0.f, 0.f, 0.f, 0.f}};
  const bf16x8 a0 = *(const bf16x8*)&kT16[sw(w * 16 + fr, fk)];
  const bf16x8 a1 = *(const bf16x8*)&kT16[sw(w * 16 + fr, fk + 32)];
#pragma unroll
  for (int cb = 0; cb < 4; ++cb) {
    const bf16x8 b0 = *(const bf16x8*)&vT16[sw(cb * 16 + fr, fk)];
    const bf16x8 b1 = *(const bf16x8*)&vT16[sw(cb * 16 + fr, fk + 32)];
    acc[cb] = __builtin_amdgcn_mfma_f32_16x16x32_bf16(a0, b0, acc[cb], 0, 0, 0);
    acc[cb] = __builtin_amdgcn_mfma_f32_16x16x32_bf16(a1, b1, acc[cb], 0, 0, 0);
  }
  float* outp = KV + (size_t)bc * DH_ * DH_;
#pragma unroll
  for (int r = 0; r < 4; ++r) {
    const int d = w * 16 + (lane >> 4) * 4 + r;
#pragma unroll
    for (int cb = 0; cb < 4; ++cb) outp[d * DH_ + cb * 16 + fr] = acc[cb][r];
  }
}

// ---------------------------------------------------------------------------
// MFMA attention with inline KV prefix (fully-unrolled masked sum over raw
// chunk KVs — independent pipelined loads, L2-resident).
// X = (qp @ KVp + tril(qp k^T) @ v') * salloc, bf16 out.
// ---------------------------------------------------------------------------
__global__ __launch_bounds__(256) void attn_k(const unsigned short* __restrict__ Q16,
                                              const unsigned short* __restrict__ K16,
                                              const unsigned short* __restrict__ V16,
                                              const float* __restrict__ KVraw,
                                              const float* __restrict__ qscale,
                                              const float* __restrict__ salloc,
                                              const float* __restrict__ comp,
                                              unsigned short* __restrict__ X) {
  const int bc = blockIdx.x;
  const int bh = bc >> 4, c = bc & (NC_ - 1);
  const int bb = bh >> 3, hh = bh & (H_ - 1);
  const int g = bc * CT_;
  __shared__ __align__(16) unsigned short qp16[64 * 64];  // [l][d]
  __shared__ __align__(16) unsigned short k16[64 * 64];   // [j][d]
  __shared__ __align__(16) unsigned short vT16[64 * 64];  // [m][j] = v'[j][m]
  __shared__ __align__(16) unsigned short kvT16[64 * 64]; // [m][d] = KVp[d][m]
  __shared__ __align__(16) unsigned short S16[64 * 64];   // [l][j] masked scores
  const int tid = threadIdx.x;
#pragma unroll
  for (int it = 0; it < 2; ++it) {
    const int i8 = it * 256 + tid;
    const int r = i8 >> 3, d0 = (i8 & 7) << 3;
    const bf16x8 qv = *(const bf16x8*)&Q16[(size_t)g * DH_ + i8 * 8];
    const bf16x8 kv = *(const bf16x8*)&K16[(size_t)g * DH_ + i8 * 8];
    const bf16x8 vv = *(const bf16x8*)&V16[(size_t)g * DH_ + i8 * 8];
    const float qs = qscale[g + r];
    const float cl = comp[g + r];
    bf16x8 pq;
#pragma unroll
    for (int j = 0; j < 8; ++j) pq[j] = (short)f2bf(bf2f((unsigned short)qv[j]) * qs);
    *(bf16x8*)&qp16[sw(r, d0)] = pq;
    *(bf16x8*)&k16[sw(r, d0)] = kv;
#pragma unroll
    for (int j = 0; j < 8; ++j)
      vT16[sw(d0 + j, r)] = f2bf(bf2f((unsigned short)vv[j]) * cl);
  }
  // kvT = transposed exclusive prefix: unrolled masked sum over raw chunk KVs
  {
    const float* kvbh = KVraw + (size_t)bh * NC_ * DH_ * DH_;
    for (int i4 = tid; i4 < DH_ * DH_ / 4; i4 += 256) {
      const int d = i4 >> 4, mg = (i4 & 15) << 2;
      float s0 = 0.f, s1 = 0.f, s2 = 0.f, s3 = 0.f;
#pragma unroll
      for (int cc = 0; cc < NC_; ++cc) {
        const float4 t = *(const float4*)&kvbh[(size_t)cc * (DH_ * DH_) + d * DH_ + mg];
        const float msk = (cc < c) ? 1.f : 0.f;
        s0 += t.x * msk; s1 += t.y * msk; s2 += t.z * msk; s3 += t.w * msk;
      }
      kvT16[sw(mg + 0, d)] = f2bf(s0);
      kvT16[sw(mg + 1, d)] = f2bf(s1);
      kvT16[sw(mg + 2, d)] = f2bf(s2);
      kvT16[sw(mg + 3, d)] = f2bf(s3);
    }
  }
  __syncthreads();

  const int lane = tid & 63, w = tid >> 6;
  const int fr = lane & 15, fk = (lane >> 4) << 3;
  const int arow = w * 16 + fr;
  f32x4 accX[4] = {{0.f, 0.f, 0.f, 0.f}, {0.f, 0.f, 0.f, 0.f},
                   {0.f, 0.f, 0.f, 0.f}, {0.f, 0.f, 0.f, 0.f}};
  f32x4 accS[4] = {{0.f, 0.f, 0.f, 0.f}, {0.f, 0.f, 0.f, 0.f},
                   {0.f, 0.f, 0.f, 0.f}, {0.f, 0.f, 0.f, 0.f}};

  const bf16x8 aq0 = *(const bf16x8*)&qp16[sw(arow, fk)];
  const bf16x8 aq1 = *(const bf16x8*)&qp16[sw(arow, fk + 32)];
#pragma unroll
  for (int cb = 0; cb < 4; ++cb) {
    const int bcol = cb * 16 + fr;
    const bf16x8 bv0 = *(const bf16x8*)&kvT16[sw(bcol, fk)];
    const bf16x8 bv1 = *(const bf16x8*)&kvT16[sw(bcol, fk + 32)];
    accX[cb] = __builtin_amdgcn_mfma_f32_16x16x32_bf16(aq0, bv0, accX[cb], 0, 0, 0);
    accX[cb] = __builtin_amdgcn_mfma_f32_16x16x32_bf16(aq1, bv1, accX[cb], 0, 0, 0);
    const bf16x8 bk0 = *(const bf16x8*)&k16[sw(bcol, fk)];
    const bf16x8 bk1 = *(const bf16x8*)&k16[sw(bcol, fk + 32)];
    accS[cb] = __builtin_amdgcn_mfma_f32_16x16x32_bf16(aq0, bk0, accS[cb], 0, 0, 0);
    accS[cb] = __builtin_amdgcn_mfma_f32_16x16x32_bf16(aq1, bk1, accS[cb], 0, 0, 0);
  }
#pragma unroll
  for (int cb = 0; cb < 4; ++cb) {
#pragma unroll
    for (int r = 0; r < 4; ++r) {
      const int l = w * 16 + (lane >> 4) * 4 + r;
      const int j = cb * 16 + fr;
      S16[sw(l, j)] = (j <= l) ? f2bf(accS[cb][r]) : (unsigned short)0;
    }
  }
  __syncthreads();
  const bf16x8 as0 = *(const bf16x8*)&S16[sw(arow, fk)];
  const bf16x8 as1 = *(const bf16x8*)&S16[sw(arow, fk + 32)];
#pragma unroll
  for (int cb = 0; cb < 4; ++cb) {
    const int bcol = cb * 16 + fr;
    const bf16x8 bv0 = *(const bf16x8*)&vT16[sw(bcol, fk)];
    const bf16x8 bv1 = *(const bf16x8*)&vT16[sw(bcol, fk + 32)];
    accX[cb] = __builtin_amdgcn_mfma_f32_16x16x32_bf16(as0, bv0, accX[cb], 0, 0, 0);
    accX[cb] = __builtin_amdgcn_mfma_f32_16x16x32_bf16(as1, bv1, accX[cb], 0, 0, 0);
  }
#pragma unroll
  for (int r = 0; r < 4; ++r) {
    const int l = w * 16 + (lane >> 4) * 4 + r;
    const float sal = salloc[g + l];
    const size_t rowbase = ((size_t)(bb * L_ + c * CT_ + l)) * D_ + hh * DH_;
#pragma unroll
    for (int cb = 0; cb < 4; ++cb) {
      const int m = cb * 16 + fr;
      X[rowbase + m] = f2bf(accX[cb][r] * sal);
    }
  }
}

// ---------------------------------------------------------------------------
// Output GEMM: d_out = X(bf16) @ WoT(bf16 [n][k]) + bo. All-bf16 staging.
// ---------------------------------------------------------------------------
__global__ __launch_bounds__(256) void gemm_out_k(const unsigned short* __restrict__ A,
                                                  const unsigned short* __restrict__ WoT,
                                                  const float* __restrict__ bias,
                                                  float* __restrict__ out) {
  __shared__ __align__(16) short Als[64 * 40];
  __shared__ __align__(16) short Bls[64 * 40];
  const int tid = threadIdx.x;
  const int m0 = blockIdx.x * 64, n0 = blockIdx.y * 64;
  const int arow = tid >> 2, akq = (tid & 3) << 3;
  const int lane = tid & 63, wid = tid >> 6;
  const int wr = wid >> 1, wc = wid & 1;
  const int lrow = lane & 15, lk = (lane >> 4) << 3;

  f32x4 acc[2][2] = {{{0.f, 0.f, 0.f, 0.f}, {0.f, 0.f, 0.f, 0.f}},
                     {{0.f, 0.f, 0.f, 0.f}, {0.f, 0.f, 0.f, 0.f}}};
  bf16x8 pa, pb;
  auto loadAB = [&](int kt) {
    pa = *(const bf16x8*)&A[(size_t)(m0 + arow) * D_ + kt + akq];
    pb = *(const bf16x8*)&WoT[(size_t)(n0 + arow) * D_ + kt + akq];
  };
  auto writeLDS = [&]() {
    *(bf16x8*)&Als[arow * 40 + akq] = pa;
    *(bf16x8*)&Bls[arow * 40 + akq] = pb;
  };
  auto compute = [&]() {
    bf16x8 a0 = *(const bf16x8*)&Als[(wr * 32 + lrow) * 40 + lk];
    bf16x8 a1 = *(const bf16x8*)&Als[(wr * 32 + 16 + lrow) * 40 + lk];
    bf16x8 b0 = *(const bf16x8*)&Bls[(wc * 32 + lrow) * 40 + lk];
    bf16x8 b1 = *(const bf16x8*)&Bls[(wc * 32 + 16 + lrow) * 40 + lk];
    acc[0][0] = __builtin_amdgcn_mfma_f32_16x16x32_bf16(a0, b0, acc[0][0], 0, 0, 0);
    acc[0][1] = __builtin_amdgcn_mfma_f32_16x16x32_bf16(a0, b1, acc[0][1], 0, 0, 0);
    acc[1][0] = __builtin_amdgcn_mfma_f32_16x16x32_bf16(a1, b0, acc[1][0], 0, 0, 0);
    acc[1][1] = __builtin_amdgcn_mfma_f32_16x16x32_bf16(a1, b1, acc[1][1], 0, 0, 0);
  };

  loadAB(0);
  writeLDS();
  for (int kt = 32; kt < D_; kt += 32) {
    loadAB(kt);
    __syncthreads();
    compute();
    __syncthreads();
    writeLDS();
  }
  __syncthreads();
  compute();

#pragma unroll
  for (int j = 0; j < 2; ++j) {
    const int col = n0 + wc * 32 + j * 16 + lrow;
    const float bv4 = bias[col];
#pragma unroll
    for (int i = 0; i < 2; ++i) {
#pragma unroll
      for (int r = 0; r < 4; ++r) {
        const int row = m0 + wr * 32 + i * 16 + (lane >> 4) * 4 + r;
        out[(size_t)row * D_ + col] = acc[i][j][r] + bv4;
      }
    }
  }
}

// ---------------------------------------------------------------------------
extern "C" void kernel_launch(void* const* d_in, const int* in_sizes, int n_in,
                              void* d_out, int out_size, void* d_ws, size_t ws_size,
                              hipStream_t stream) {
  (void)in_sizes; (void)n_in; (void)out_size; (void)ws_size;
  const float* queries = (const float*)d_in[0];
  const float* keys    = (const float*)d_in[1];
  const float* values  = (const float*)d_in[2];
  const float* Wq = (const float*)d_in[3];
  const float* bq = (const float*)d_in[4];
  const float* Wk = (const float*)d_in[5];
  const float* bk = (const float*)d_in[6];
  const float* Wv = (const float*)d_in[7];
  const float* bv = (const float*)d_in[8];
  const float* Wo = (const float*)d_in[9];
  const float* bo = (const float*)d_in[10];

  const size_t seg = (size_t)BH_ * L_ * DH_;  // 1,048,576 elements
  unsigned short* Qb = (unsigned short*)d_ws;          // bf16 [BH,L,Dh]
  unsigned short* Kb = Qb + seg;
  unsigned short* Vb = Kb + seg;
  unsigned short* WT = Vb + seg;                       // 4 x [512][512] bf16
  unsigned short* Xb16 = WT + (size_t)4 * D_ * D_;     // [BL, D] bf16
  float* KVb = (float*)(Xb16 + (size_t)BL_ * D_);      // [BH, NC, 64, 64] raw
  float* p   = KVb + (size_t)BH_ * NC_ * DH_ * DH_;
  float* qscale = p; p += BH_ * L_;
  float* salloc = p; p += BH_ * L_;
  float* comp   = p; p += BH_ * L_;
  float* si_a   = p; p += BH_ * L_;
  float* so_a   = p; p += BH_ * L_;
  float* e_a    = p; p += BH_ * L_;
  float* sumQ   = p; p += BH_ * NC_ * DH_;
  float* sumK   = p; p += BH_ * NC_ * DH_;
  float* sumQSI = p; p += BH_ * NC_ * DH_;
  float* sumKSO = p; p += BH_ * NC_ * DH_;
  float* sumE   = p; p += BH_ * NC_;

  convw_k<<<dim3(8, 8, 4), 256, 0, stream>>>(Wq, Wk, Wv, Wo, WT);
  proj3_k<<<dim3(BL_ / 64, D_ / 64, 3), 256, 0, stream>>>(
      queries, keys, values, WT, bq, bk, bv, Qb, Kb, Vb, sumQ, sumK);
  flow_phase1_k<<<BH_ * NC_, 256, 0, stream>>>(Qb, Kb, sumQ, sumK,
                                               qscale, si_a, so_a, sumQSI, sumKSO);
  flow_phase2_k<<<BH_ * NC_, 256, 0, stream>>>(Qb, Kb, sumQSI, sumKSO, si_a, so_a,
                                               salloc, e_a, sumE);
  flow_ckv_k<<<BH_ * NC_, 256, 0, stream>>>(Kb, Vb, e_a, sumE, comp, KVb);
  attn_k<<<BH_ * NC_, 256, 0, stream>>>(Qb, Kb, Vb, KVb, qscale, salloc, comp, Xb16);
  gemm_out_k<<<dim3(BL_ / 64, D_ / 64), 256, 0, stream>>>(
      Xb16, WT + (size_t)3 * D_ * D_, bo, (float*)d_out);
}

// Round 11
// 63.447 us; speedup vs baseline: 1.0301x; 1.0301x over previous
//
#include <hip/hip_runtime.h>
#include <math.h>

#define EPSF 1e-6f

constexpr int B_  = 2;
constexpr int L_  = 1024;
constexpr int D_  = 512;
constexpr int H_  = 8;
constexpr int DH_ = 64;
constexpr int BL_ = B_ * L_;   // 2048
constexpr int BH_ = B_ * H_;   // 16
constexpr int CT_ = 64;        // chunk length
constexpr int NC_ = L_ / CT_;  // 16 chunks

typedef __attribute__((ext_vector_type(8))) short bf16x8;
typedef __attribute__((ext_vector_type(4))) float f32x4;

__device__ __forceinline__ unsigned short f2bf(float f) {
  union { float f; unsigned int u; } v; v.f = f;
  const unsigned int u = v.u;
  return (unsigned short)((u + 0x7FFFu + ((u >> 16) & 1u)) >> 16);  // RNE
}
__device__ __forceinline__ float bf2f(unsigned short u) {
  union { unsigned int u; float f; } v; v.u = ((unsigned int)u) << 16;
  return v.f;
}

// Swizzled ushort index for a [64][64] bf16 LDS tile: conflict-free b128 reads.
__device__ __forceinline__ int sw(int row, int col) {
  return row * 64 + (col ^ ((row & 7) << 3));
}

// ---------------------------------------------------------------------------
// Fused projection GEMMs, 64x64 tile, BK=64 (16 barriers total), 768 blocks =
// 3/CU (z = 0:Q, 1:K, 2:V): out = sigmoid?(A @ W + b) stored BF16 permuted to
// [B,H,L,Dh]; z<2 also writes per-(chunk,head) column sums of ROUNDED values.
// ---------------------------------------------------------------------------
__global__ __launch_bounds__(256) void proj3_k(const float* __restrict__ Qin,
                                               const float* __restrict__ Kin,
                                               const float* __restrict__ Vin,
                                               const float* __restrict__ Wq,
                                               const float* __restrict__ bq,
                                               const float* __restrict__ Wk,
                                               const float* __restrict__ bk,
                                               const float* __restrict__ Wv,
                                               const float* __restrict__ bv,
                                               unsigned short* __restrict__ Qb,
                                               unsigned short* __restrict__ Kb,
                                               unsigned short* __restrict__ Vb,
                                               float* __restrict__ sumQ,
                                               float* __restrict__ sumK) {
  const int z = blockIdx.z;
  const float* A    = (z == 0) ? Qin : (z == 1) ? Kin : Vin;
  const float* W    = (z == 0) ? Wq  : (z == 1) ? Wk  : Wv;
  const float* bias = (z == 0) ? bq  : (z == 1) ? bk  : bv;
  unsigned short* out = (z == 0) ? Qb : (z == 1) ? Kb : Vb;
  float* csum       = (z == 0) ? sumQ : (z == 1) ? sumK : nullptr;
  const bool sig = (z < 2);

  __shared__ __align__(16) short Als[64 * 72];  // [row][k0..64], pad 72
  __shared__ __align__(16) short Bls[64 * 72];  // [col][k0..64]
  const int tid = threadIdx.x;
  const int m0 = blockIdx.x * 64, n0 = blockIdx.y * 64;
  const int arow = tid >> 2, ak0 = (tid & 3) << 4;  // 16 k-contig per thread
  const int bcol = tid & 63, bk0 = (tid >> 6) << 4; // 16 k-strided per thread
  const int lane = tid & 63, wid = tid >> 6;
  const int wr = wid >> 1, wc = wid & 1;
  const int lrow = lane & 15, lk = (lane >> 4) << 3;

  f32x4 acc[2][2] = {{{0.f, 0.f, 0.f, 0.f}, {0.f, 0.f, 0.f, 0.f}},
                     {{0.f, 0.f, 0.f, 0.f}, {0.f, 0.f, 0.f, 0.f}}};
  float ra[16], rb[16];

  auto loadAB = [&](int kt) {
#pragma unroll
    for (int j = 0; j < 4; ++j) {
      const float4 f = *(const float4*)&A[(size_t)(m0 + arow) * D_ + kt + ak0 + 4 * j];
      ra[4 * j + 0] = f.x; ra[4 * j + 1] = f.y; ra[4 * j + 2] = f.z; ra[4 * j + 3] = f.w;
    }
    const float* gw = &W[(size_t)(kt + bk0) * D_ + n0 + bcol];
#pragma unroll
    for (int j = 0; j < 16; ++j) rb[j] = gw[(size_t)j * D_];
  };
  auto writeLDS = [&]() {
    bf16x8 pa0, pa1, pb0, pb1;
#pragma unroll
    for (int j = 0; j < 8; ++j) {
      pa0[j] = (short)f2bf(ra[j]);
      pa1[j] = (short)f2bf(ra[j + 8]);
      pb0[j] = (short)f2bf(rb[j]);
      pb1[j] = (short)f2bf(rb[j + 8]);
    }
    *(bf16x8*)&Als[arow * 72 + ak0] = pa0;
    *(bf16x8*)&Als[arow * 72 + ak0 + 8] = pa1;
    *(bf16x8*)&Bls[bcol * 72 + bk0] = pb0;
    *(bf16x8*)&Bls[bcol * 72 + bk0 + 8] = pb1;
  };
  auto compute = [&]() {
#pragma unroll
    for (int ks = 0; ks < 2; ++ks) {
      const int ko = ks * 32 + lk;
      bf16x8 a0 = *(const bf16x8*)&Als[(wr * 32 + lrow) * 72 + ko];
      bf16x8 a1 = *(const bf16x8*)&Als[(wr * 32 + 16 + lrow) * 72 + ko];
      bf16x8 b0 = *(const bf16x8*)&Bls[(wc * 32 + lrow) * 72 + ko];
      bf16x8 b1 = *(const bf16x8*)&Bls[(wc * 32 + 16 + lrow) * 72 + ko];
      acc[0][0] = __builtin_amdgcn_mfma_f32_16x16x32_bf16(a0, b0, acc[0][0], 0, 0, 0);
      acc[0][1] = __builtin_amdgcn_mfma_f32_16x16x32_bf16(a0, b1, acc[0][1], 0, 0, 0);
      acc[1][0] = __builtin_amdgcn_mfma_f32_16x16x32_bf16(a1, b0, acc[1][0], 0, 0, 0);
      acc[1][1] = __builtin_amdgcn_mfma_f32_16x16x32_bf16(a1, b1, acc[1][1], 0, 0, 0);
    }
  };

  loadAB(0);
  writeLDS();
  for (int kt = 64; kt < D_; kt += 64) {
    loadAB(kt);       // register prefetch of next K-tile
    __syncthreads();
    compute();
    __syncthreads();
    writeLDS();
  }
  __syncthreads();
  compute();

  const int b = m0 >> 10, h = n0 >> 6;
  float psum[2] = {0.f, 0.f};
#pragma unroll
  for (int j = 0; j < 2; ++j) {
    const int col = n0 + wc * 32 + j * 16 + lrow;
    const float bv4 = bias[col];
    const int dh = col & 63;
#pragma unroll
    for (int i = 0; i < 2; ++i) {
#pragma unroll
      for (int r = 0; r < 4; ++r) {
        const int row = m0 + wr * 32 + i * 16 + (lane >> 4) * 4 + r;
        float x = acc[i][j][r] + bv4;
        if (sig) x = 1.0f / (1.0f + expf(-x));
        const unsigned short ub = f2bf(x);
        const int l = row & (L_ - 1);
        out[(((size_t)(b * H_ + h)) * L_ + l) * DH_ + dh] = ub;
        psum[j] += bf2f(ub);  // sum the ROUNDED value: exact decomposition
      }
    }
  }
  if (csum) {
    float* sumS = (float*)Als;
#pragma unroll
    for (int j = 0; j < 2; ++j) {
      psum[j] += __shfl_xor(psum[j], 16);
      psum[j] += __shfl_xor(psum[j], 32);
      if ((lane >> 4) == 0) sumS[wr * 64 + wc * 32 + j * 16 + lrow] = psum[j];
    }
    __syncthreads();
    if (tid < 64) {
      const int c = (m0 & (L_ - 1)) >> 6;
      const int bc = (b * H_ + h) * NC_ + c;
      csum[bc * DH_ + tid] = sumS[tid] + sumS[64 + tid];
    }
  }
}

// ---------------------------------------------------------------------------
// Flow phase 1: 256 thr, 4-wave d-split scans. bf16 q/k in, fp32 LDS/scans.
// ---------------------------------------------------------------------------
__global__ __launch_bounds__(256) void flow_phase1_k(const unsigned short* __restrict__ Qb,
                                                     const unsigned short* __restrict__ Kb,
                                                     const float* __restrict__ sumQ,
                                                     const float* __restrict__ sumK,
                                                     float* __restrict__ qscale,
                                                     float* __restrict__ si_a,
                                                     float* __restrict__ so_a,
                                                     float* __restrict__ sumQSI,
                                                     float* __restrict__ sumKSO) {
  const int bc = blockIdx.x, bh = bc >> 4, c = bc & (NC_ - 1);
  const int g = bc * CT_;
  const int tid = threadIdx.x, lane = tid & 63, w = tid >> 6;
  __shared__ float qS[64][65], kS[64][65];
  __shared__ float pqS[64], pkS[64];
  __shared__ float aS[4][64], bS[4][64];
  __shared__ float siS[64], soS[64];
#pragma unroll
  for (int it = 0; it < 2; ++it) {
    const int i8 = it * 256 + tid;
    const int row = i8 >> 3, d0 = (i8 & 7) << 3;
    const bf16x8 qv = *(const bf16x8*)&Qb[(size_t)g * DH_ + i8 * 8];
    const bf16x8 kv = *(const bf16x8*)&Kb[(size_t)g * DH_ + i8 * 8];
#pragma unroll
    for (int j = 0; j < 8; ++j) {
      qS[row][d0 + j] = bf2f((unsigned short)qv[j]);
      kS[row][d0 + j] = bf2f((unsigned short)kv[j]);
    }
  }
  if (tid < 64) {
    float pq = 0.f, pk = 0.f;
    for (int cc = 0; cc < c; ++cc) {
      pq += sumQ[(bh * NC_ + cc) * DH_ + tid];
      pk += sumK[(bh * NC_ + cc) * DH_ + tid];
    }
    pqS[tid] = pq; pkS[tid] = pk;
  }
  __syncthreads();
  float ap = 0.f, bp = 0.f;
  for (int dd = 0; dd < 16; ++dd) {
    const int d = w * 16 + dd;
    const float qv = qS[lane][d];
    const float kv = kS[lane][d];
    float ck = kv, cq = qv;
#pragma unroll
    for (int off = 1; off < 64; off <<= 1) {
      const float t1 = __shfl_up(ck, off);
      const float t2 = __shfl_up(cq, off);
      ck += (lane >= off) ? t1 : 0.f;
      cq += (lane >= off) ? t2 : 0.f;
    }
    ck += pkS[d];
    cq += pqS[d];
    ap += (qv + EPSF) * (ck + EPSF);
    bp += (kv + EPSF) * (cq + EPSF);
  }
  aS[w][lane] = ap; bS[w][lane] = bp;
  __syncthreads();
  const float normal = (float)(c * CT_ + lane + 1);
  if (w == 0) {
    const float a = aS[0][lane] + aS[1][lane] + aS[2][lane] + aS[3][lane];
    const float b = bS[0][lane] + bS[1][lane] + bS[2][lane] + bS[3][lane];
    const float si = normal / a, so = normal / b;
    qscale[g + lane] = 1.0f / a;
    si_a[g + lane] = si;
    so_a[g + lane] = so;
    siS[lane] = si; soS[lane] = so;
  }
  __syncthreads();
  float sq = 0.f, sk = 0.f;
#pragma unroll
  for (int li = 0; li < 16; ++li) {
    const int l = w * 16 + li;
    sq += qS[l][lane] * siS[l];
    sk += kS[l][lane] * soS[l];
  }
  aS[w][lane] = sq; bS[w][lane] = sk;
  __syncthreads();
  if (tid < 64) {
    sumQSI[bc * DH_ + tid] = aS[0][tid] + aS[1][tid] + aS[2][tid] + aS[3][tid];
    sumKSO[bc * DH_ + tid] = bS[0][tid] + bS[1][tid] + bS[2][tid] + bS[3][tid];
  }
}

// ---------------------------------------------------------------------------
// Flow phase 2: 256 thr, 4-wave d-split. Outputs salloc, e, chunk sumE.
// ---------------------------------------------------------------------------
__global__ __launch_bounds__(256) void flow_phase2_k(const unsigned short* __restrict__ Qb,
                                                     const unsigned short* __restrict__ Kb,
                                                     const float* __restrict__ sumQSI,
                                                     const float* __restrict__ sumKSO,
                                                     const float* __restrict__ si_a,
                                                     const float* __restrict__ so_a,
                                                     float* __restrict__ salloc,
                                                     float* __restrict__ e_a,
                                                     float* __restrict__ sumE) {
  const int bc = blockIdx.x, bh = bc >> 4, c = bc & (NC_ - 1);
  const int g = bc * CT_;
  const int tid = threadIdx.x, lane = tid & 63, w = tid >> 6;
  __shared__ float qS[64][65], kS[64][65];
  __shared__ float pqS[64], pkS[64];
  __shared__ float aS[4][64], bS[4][64];
#pragma unroll
  for (int it = 0; it < 2; ++it) {
    const int i8 = it * 256 + tid;
    const int row = i8 >> 3, d0 = (i8 & 7) << 3;
    const bf16x8 qv = *(const bf16x8*)&Qb[(size_t)g * DH_ + i8 * 8];
    const bf16x8 kv = *(const bf16x8*)&Kb[(size_t)g * DH_ + i8 * 8];
#pragma unroll
    for (int j = 0; j < 8; ++j) {
      qS[row][d0 + j] = bf2f((unsigned short)qv[j]);
      kS[row][d0 + j] = bf2f((unsigned short)kv[j]);
    }
  }
  if (tid < 64) {
    float pq = 0.f, pk = 0.f;
    for (int cc = 0; cc < c; ++cc) {
      pq += sumQSI[(bh * NC_ + cc) * DH_ + tid];
      pk += sumKSO[(bh * NC_ + cc) * DH_ + tid];
    }
    pqS[tid] = pq; pkS[tid] = pk;
  }
  __syncthreads();
  const float si = si_a[g + lane];
  const float so = so_a[g + lane];
  float c1p = 0.f, c2p = 0.f;
  for (int dd = 0; dd < 16; ++dd) {
    const int d = w * 16 + dd;
    const float qv = qS[lane][d];
    const float kv = kS[lane][d];
    float ckso = kv * so, cqsi = qv * si;
#pragma unroll
    for (int off = 1; off < 64; off <<= 1) {
      const float t1 = __shfl_up(ckso, off);
      const float t2 = __shfl_up(cqsi, off);
      ckso += (lane >= off) ? t1 : 0.f;
      cqsi += (lane >= off) ? t2 : 0.f;
    }
    ckso += pkS[d];
    cqsi += pqS[d];
    c1p += (qv + EPSF) * (ckso + EPSF);
    c2p += (kv + EPSF) * (cqsi + EPSF);
  }
  aS[w][lane] = c1p; bS[w][lane] = c2p;
  __syncthreads();
  if (w == 0) {
    const float c1 = aS[0][lane] + aS[1][lane] + aS[2][lane] + aS[3][lane];
    const float c2 = bS[0][lane] + bS[1][lane] + bS[2][lane] + bS[3][lane];
    const float normal = (float)(c * CT_ + lane + 1);
    const float cs_sink = c1 / normal;
    salloc[g + lane] = 1.0f / (1.0f + expf(-cs_sink));
    float cs_src = c2 / normal;
    cs_src = fminf(1.0f, fmaxf(-1.0f, cs_src));
    const float e = expf(cs_src);
    e_a[g + lane] = e;
    float tot = e;
#pragma unroll
    for (int off = 32; off; off >>= 1) tot += __shfl_xor(tot, off);
    if (lane == 0) sumE[bc] = tot;
  }
}

// ---------------------------------------------------------------------------
// Fused: source_competition (inline prefix of sumE) + MFMA chunk-KV:
// KV[bc][d][m] = sum_l k[l,d] * (v[l,m]*comp[l])  ==  k^T @ v'.  (raw, not
// prefixed — attn does the prefix inline.)
// ---------------------------------------------------------------------------
__global__ __launch_bounds__(256) void flow_ckv_k(const unsigned short* __restrict__ K16,
                                                  const unsigned short* __restrict__ V16,
                                                  const float* __restrict__ e_a,
                                                  const float* __restrict__ sumE,
                                                  float* __restrict__ comp,
                                                  float* __restrict__ KV) {
  const int bc = blockIdx.x, bh = bc >> 4, c = bc & (NC_ - 1);
  const int g = bc * CT_;
  const int tid = threadIdx.x;
  __shared__ float compS[CT_];
  __shared__ __align__(16) unsigned short kT16[64 * 64];  // [d][l]
  __shared__ __align__(16) unsigned short vT16[64 * 64];  // [m][l] = v'[l][m]
  if (tid < 64) {
    const int lane = tid;
    const float e = e_a[g + lane];
    float se = (lane < c) ? sumE[bh * NC_ + lane] : 0.f;
#pragma unroll
    for (int off = 32; off; off >>= 1) se += __shfl_xor(se, off);
    float s = e;
#pragma unroll
    for (int off = 1; off < 64; off <<= 1) {
      const float t = __shfl_up(s, off);
      s += (lane >= off) ? t : 0.f;
    }
    const float cf = e / (se + s) * (float)(c * CT_ + lane + 1);
    compS[lane] = cf;
    comp[g + lane] = cf;
  }
  __syncthreads();
#pragma unroll
  for (int it = 0; it < 2; ++it) {
    const int i8 = it * 256 + tid;
    const int l = i8 >> 3, d0 = (i8 & 7) << 3;
    const bf16x8 kv = *(const bf16x8*)&K16[(size_t)g * DH_ + i8 * 8];
    const bf16x8 vv = *(const bf16x8*)&V16[(size_t)g * DH_ + i8 * 8];
    const float cl = compS[l];
#pragma unroll
    for (int j = 0; j < 8; ++j) {
      kT16[sw(d0 + j, l)] = (unsigned short)kv[j];
      vT16[sw(d0 + j, l)] = f2bf(bf2f((unsigned short)vv[j]) * cl);
    }
  }
  __syncthreads();
  const int lane = tid & 63, w = tid >> 6;
  const int fr = lane & 15, fk = (lane >> 4) << 3;
  f32x4 acc[4] = {{0.f, 0.f, 0.f, 0.f}, {0.f, 0.f, 0.f, 0.f},
                  {0.f, 0.f, 0.f, 0.f}, {0.f, 0.f, 0.f, 0.f}};
  const bf16x8 a0 = *(const bf16x8*)&kT16[sw(w * 16 + fr, fk)];
  const bf16x8 a1 = *(const bf16x8*)&kT16[sw(w * 16 + fr, fk + 32)];
#pragma unroll
  for (int cb = 0; cb < 4; ++cb) {
    const bf16x8 b0 = *(const bf16x8*)&vT16[sw(cb * 16 + fr, fk)];
    const bf16x8 b1 = *(const bf16x8*)&vT16[sw(cb * 16 + fr, fk + 32)];
    acc[cb] = __builtin_amdgcn_mfma_f32_16x16x32_bf16(a0, b0, acc[cb], 0, 0, 0);
    acc[cb] = __builtin_amdgcn_mfma_f32_16x16x32_bf16(a1, b1, acc[cb], 0, 0, 0);
  }
  float* outp = KV + (size_t)bc * DH_ * DH_;
#pragma unroll
  for (int r = 0; r < 4; ++r) {
    const int d = w * 16 + (lane >> 4) * 4 + r;
#pragma unroll
    for (int cb = 0; cb < 4; ++cb) outp[d * DH_ + cb * 16 + fr] = acc[cb][r];
  }
}

// ---------------------------------------------------------------------------
// MFMA attention with inline KV prefix (fully-unrolled masked sum over raw
// chunk KVs — independent pipelined loads, L2-resident).
// X = (qp @ KVp + tril(qp k^T) @ v') * salloc, bf16 out.
// ---------------------------------------------------------------------------
__global__ __launch_bounds__(256) void attn_k(const unsigned short* __restrict__ Q16,
                                              const unsigned short* __restrict__ K16,
                                              const unsigned short* __restrict__ V16,
                                              const float* __restrict__ KVraw,
                                              const float* __restrict__ qscale,
                                              const float* __restrict__ salloc,
                                              const float* __restrict__ comp,
                                              unsigned short* __restrict__ X) {
  const int bc = blockIdx.x;
  const int bh = bc >> 4, c = bc & (NC_ - 1);
  const int bb = bh >> 3, hh = bh & (H_ - 1);
  const int g = bc * CT_;
  __shared__ __align__(16) unsigned short qp16[64 * 64];  // [l][d]
  __shared__ __align__(16) unsigned short k16[64 * 64];   // [j][d]
  __shared__ __align__(16) unsigned short vT16[64 * 64];  // [m][j] = v'[j][m]
  __shared__ __align__(16) unsigned short kvT16[64 * 64]; // [m][d] = KVp[d][m]
  __shared__ __align__(16) unsigned short S16[64 * 64];   // [l][j] masked scores
  const int tid = threadIdx.x;
#pragma unroll
  for (int it = 0; it < 2; ++it) {
    const int i8 = it * 256 + tid;
    const int r = i8 >> 3, d0 = (i8 & 7) << 3;
    const bf16x8 qv = *(const bf16x8*)&Q16[(size_t)g * DH_ + i8 * 8];
    const bf16x8 kv = *(const bf16x8*)&K16[(size_t)g * DH_ + i8 * 8];
    const bf16x8 vv = *(const bf16x8*)&V16[(size_t)g * DH_ + i8 * 8];
    const float qs = qscale[g + r];
    const float cl = comp[g + r];
    bf16x8 pq;
#pragma unroll
    for (int j = 0; j < 8; ++j) pq[j] = (short)f2bf(bf2f((unsigned short)qv[j]) * qs);
    *(bf16x8*)&qp16[sw(r, d0)] = pq;
    *(bf16x8*)&k16[sw(r, d0)] = kv;
#pragma unroll
    for (int j = 0; j < 8; ++j)
      vT16[sw(d0 + j, r)] = f2bf(bf2f((unsigned short)vv[j]) * cl);
  }
  // kvT = transposed exclusive prefix: unrolled masked sum over raw chunk KVs
  {
    const float* kvbh = KVraw + (size_t)bh * NC_ * DH_ * DH_;
    for (int i4 = tid; i4 < DH_ * DH_ / 4; i4 += 256) {
      const int d = i4 >> 4, mg = (i4 & 15) << 2;
      float s0 = 0.f, s1 = 0.f, s2 = 0.f, s3 = 0.f;
#pragma unroll
      for (int cc = 0; cc < NC_; ++cc) {
        const float4 t = *(const float4*)&kvbh[(size_t)cc * (DH_ * DH_) + d * DH_ + mg];
        const float msk = (cc < c) ? 1.f : 0.f;
        s0 += t.x * msk; s1 += t.y * msk; s2 += t.z * msk; s3 += t.w * msk;
      }
      kvT16[sw(mg + 0, d)] = f2bf(s0);
      kvT16[sw(mg + 1, d)] = f2bf(s1);
      kvT16[sw(mg + 2, d)] = f2bf(s2);
      kvT16[sw(mg + 3, d)] = f2bf(s3);
    }
  }
  __syncthreads();

  const int lane = tid & 63, w = tid >> 6;
  const int fr = lane & 15, fk = (lane >> 4) << 3;
  const int arow = w * 16 + fr;
  f32x4 accX[4] = {{0.f, 0.f, 0.f, 0.f}, {0.f, 0.f, 0.f, 0.f},
                   {0.f, 0.f, 0.f, 0.f}, {0.f, 0.f, 0.f, 0.f}};
  f32x4 accS[4] = {{0.f, 0.f, 0.f, 0.f}, {0.f, 0.f, 0.f, 0.f},
                   {0.f, 0.f, 0.f, 0.f}, {0.f, 0.f, 0.f, 0.f}};

  const bf16x8 aq0 = *(const bf16x8*)&qp16[sw(arow, fk)];
  const bf16x8 aq1 = *(const bf16x8*)&qp16[sw(arow, fk + 32)];
#pragma unroll
  for (int cb = 0; cb < 4; ++cb) {
    const int bcol = cb * 16 + fr;
    const bf16x8 bv0 = *(const bf16x8*)&kvT16[sw(bcol, fk)];
    const bf16x8 bv1 = *(const bf16x8*)&kvT16[sw(bcol, fk + 32)];
    accX[cb] = __builtin_amdgcn_mfma_f32_16x16x32_bf16(aq0, bv0, accX[cb], 0, 0, 0);
    accX[cb] = __builtin_amdgcn_mfma_f32_16x16x32_bf16(aq1, bv1, accX[cb], 0, 0, 0);
    const bf16x8 bk0 = *(const bf16x8*)&k16[sw(bcol, fk)];
    const bf16x8 bk1 = *(const bf16x8*)&k16[sw(bcol, fk + 32)];
    accS[cb] = __builtin_amdgcn_mfma_f32_16x16x32_bf16(aq0, bk0, accS[cb], 0, 0, 0);
    accS[cb] = __builtin_amdgcn_mfma_f32_16x16x32_bf16(aq1, bk1, accS[cb], 0, 0, 0);
  }
#pragma unroll
  for (int cb = 0; cb < 4; ++cb) {
#pragma unroll
    for (int r = 0; r < 4; ++r) {
      const int l = w * 16 + (lane >> 4) * 4 + r;
      const int j = cb * 16 + fr;
      S16[sw(l, j)] = (j <= l) ? f2bf(accS[cb][r]) : (unsigned short)0;
    }
  }
  __syncthreads();
  const bf16x8 as0 = *(const bf16x8*)&S16[sw(arow, fk)];
  const bf16x8 as1 = *(const bf16x8*)&S16[sw(arow, fk + 32)];
#pragma unroll
  for (int cb = 0; cb < 4; ++cb) {
    const int bcol = cb * 16 + fr;
    const bf16x8 bv0 = *(const bf16x8*)&vT16[sw(bcol, fk)];
    const bf16x8 bv1 = *(const bf16x8*)&vT16[sw(bcol, fk + 32)];
    accX[cb] = __builtin_amdgcn_mfma_f32_16x16x32_bf16(as0, bv0, accX[cb], 0, 0, 0);
    accX[cb] = __builtin_amdgcn_mfma_f32_16x16x32_bf16(as1, bv1, accX[cb], 0, 0, 0);
  }
#pragma unroll
  for (int r = 0; r < 4; ++r) {
    const int l = w * 16 + (lane >> 4) * 4 + r;
    const float sal = salloc[g + l];
    const size_t rowbase = ((size_t)(bb * L_ + c * CT_ + l)) * D_ + hh * DH_;
#pragma unroll
    for (int cb = 0; cb < 4; ++cb) {
      const int m = cb * 16 + fr;
      X[rowbase + m] = f2bf(accX[cb][r] * sal);
    }
  }
}

// ---------------------------------------------------------------------------
// Output GEMM: d_out = X(bf16) @ Wo + bo. 64x64 tile, BK=64, 256 blocks.
// ---------------------------------------------------------------------------
__global__ __launch_bounds__(256) void gemm_out_k(const unsigned short* __restrict__ A,
                                                  const float* __restrict__ W,
                                                  const float* __restrict__ bias,
                                                  float* __restrict__ out) {
  __shared__ __align__(16) short Als[64 * 72];
  __shared__ __align__(16) short Bls[64 * 72];
  const int tid = threadIdx.x;
  const int m0 = blockIdx.x * 64, n0 = blockIdx.y * 64;
  const int arow = tid >> 2, ak0 = (tid & 3) << 4;   // 16 bf16, contiguous
  const int bcol = tid & 63, bk0 = (tid >> 6) << 4;  // 16 k-strided floats
  const int lane = tid & 63, wid = tid >> 6;
  const int wr = wid >> 1, wc = wid & 1;
  const int lrow = lane & 15, lk = (lane >> 4) << 3;

  f32x4 acc[2][2] = {{{0.f, 0.f, 0.f, 0.f}, {0.f, 0.f, 0.f, 0.f}},
                     {{0.f, 0.f, 0.f, 0.f}, {0.f, 0.f, 0.f, 0.f}}};
  bf16x8 pa0, pa1;
  float rb[16];
  auto loadAB = [&](int kt) {
    pa0 = *(const bf16x8*)&A[(size_t)(m0 + arow) * D_ + kt + ak0];
    pa1 = *(const bf16x8*)&A[(size_t)(m0 + arow) * D_ + kt + ak0 + 8];
    const float* gw = &W[(size_t)(kt + bk0) * D_ + n0 + bcol];
#pragma unroll
    for (int j = 0; j < 16; ++j) rb[j] = gw[(size_t)j * D_];
  };
  auto writeLDS = [&]() {
    bf16x8 pb0, pb1;
#pragma unroll
    for (int j = 0; j < 8; ++j) {
      pb0[j] = (short)f2bf(rb[j]);
      pb1[j] = (short)f2bf(rb[j + 8]);
    }
    *(bf16x8*)&Als[arow * 72 + ak0] = pa0;
    *(bf16x8*)&Als[arow * 72 + ak0 + 8] = pa1;
    *(bf16x8*)&Bls[bcol * 72 + bk0] = pb0;
    *(bf16x8*)&Bls[bcol * 72 + bk0 + 8] = pb1;
  };
  auto compute = [&]() {
#pragma unroll
    for (int ks = 0; ks < 2; ++ks) {
      const int ko = ks * 32 + lk;
      bf16x8 a0 = *(const bf16x8*)&Als[(wr * 32 + lrow) * 72 + ko];
      bf16x8 a1 = *(const bf16x8*)&Als[(wr * 32 + 16 + lrow) * 72 + ko];
      bf16x8 b0 = *(const bf16x8*)&Bls[(wc * 32 + lrow) * 72 + ko];
      bf16x8 b1 = *(const bf16x8*)&Bls[(wc * 32 + 16 + lrow) * 72 + ko];
      acc[0][0] = __builtin_amdgcn_mfma_f32_16x16x32_bf16(a0, b0, acc[0][0], 0, 0, 0);
      acc[0][1] = __builtin_amdgcn_mfma_f32_16x16x32_bf16(a0, b1, acc[0][1], 0, 0, 0);
      acc[1][0] = __builtin_amdgcn_mfma_f32_16x16x32_bf16(a1, b0, acc[1][0], 0, 0, 0);
      acc[1][1] = __builtin_amdgcn_mfma_f32_16x16x32_bf16(a1, b1, acc[1][1], 0, 0, 0);
    }
  };

  loadAB(0);
  writeLDS();
  for (int kt = 64; kt < D_; kt += 64) {
    loadAB(kt);
    __syncthreads();
    compute();
    __syncthreads();
    writeLDS();
  }
  __syncthreads();
  compute();

#pragma unroll
  for (int j = 0; j < 2; ++j) {
    const int col = n0 + wc * 32 + j * 16 + lrow;
    const float bv4 = bias[col];
#pragma unroll
    for (int i = 0; i < 2; ++i) {
#pragma unroll
      for (int r = 0; r < 4; ++r) {
        const int row = m0 + wr * 32 + i * 16 + (lane >> 4) * 4 + r;
        out[(size_t)row * D_ + col] = acc[i][j][r] + bv4;
      }
    }
  }
}

// ---------------------------------------------------------------------------
extern "C" void kernel_launch(void* const* d_in, const int* in_sizes, int n_in,
                              void* d_out, int out_size, void* d_ws, size_t ws_size,
                              hipStream_t stream) {
  (void)in_sizes; (void)n_in; (void)out_size; (void)ws_size;
  const float* queries = (const float*)d_in[0];
  const float* keys    = (const float*)d_in[1];
  const float* values  = (const float*)d_in[2];
  const float* Wq = (const float*)d_in[3];
  const float* bq = (const float*)d_in[4];
  const float* Wk = (const float*)d_in[5];
  const float* bk = (const float*)d_in[6];
  const float* Wv = (const float*)d_in[7];
  const float* bv = (const float*)d_in[8];
  const float* Wo = (const float*)d_in[9];
  const float* bo = (const float*)d_in[10];

  const size_t seg = (size_t)BH_ * L_ * DH_;  // 1,048,576 elements
  unsigned short* Qb = (unsigned short*)d_ws;          // bf16 [BH,L,Dh]
  unsigned short* Kb = Qb + seg;
  unsigned short* Vb = Kb + seg;
  float* KVb = (float*)(Vb + seg);                      // [BH, NC, 64, 64] raw
  float* p   = KVb + (size_t)BH_ * NC_ * DH_ * DH_;
  float* qscale = p; p += BH_ * L_;
  float* salloc = p; p += BH_ * L_;
  float* comp   = p; p += BH_ * L_;
  float* si_a   = p; p += BH_ * L_;
  float* so_a   = p; p += BH_ * L_;
  float* e_a    = p; p += BH_ * L_;
  float* sumQ   = p; p += BH_ * NC_ * DH_;
  float* sumK   = p; p += BH_ * NC_ * DH_;
  float* sumQSI = p; p += BH_ * NC_ * DH_;
  float* sumKSO = p; p += BH_ * NC_ * DH_;
  float* sumE   = p; p += BH_ * NC_;
  unsigned short* Xb16 = (unsigned short*)p;            // [BL, D] bf16

  proj3_k<<<dim3(BL_ / 64, D_ / 64, 3), 256, 0, stream>>>(
      queries, keys, values, Wq, bq, Wk, bk, Wv, bv, Qb, Kb, Vb, sumQ, sumK);
  flow_phase1_k<<<BH_ * NC_, 256, 0, stream>>>(Qb, Kb, sumQ, sumK,
                                               qscale, si_a, so_a, sumQSI, sumKSO);
  flow_phase2_k<<<BH_ * NC_, 256, 0, stream>>>(Qb, Kb, sumQSI, sumKSO, si_a, so_a,
                                               salloc, e_a, sumE);
  flow_ckv_k<<<BH_ * NC_, 256, 0, stream>>>(Kb, Vb, e_a, sumE, comp, KVb);
  attn_k<<<BH_ * NC_, 256, 0, stream>>>(Qb, Kb, Vb, KVb, qscale, salloc, comp, Xb16);
  gemm_out_k<<<dim3(BL_ / 64, D_ / 64), 256, 0, stream>>>(Xb16, Wo, bo, (float*)d_out);
}

// Round 12
// 57.813 us; speedup vs baseline: 1.1304x; 1.0975x over previous
//
#include <hip/hip_runtime.h>
#include <math.h>

#define EPSF 1e-6f

constexpr int B_  = 2;
constexpr int L_  = 1024;
constexpr int D_  = 512;
constexpr int H_  = 8;
constexpr int DH_ = 64;
constexpr int BL_ = B_ * L_;   // 2048
constexpr int BH_ = B_ * H_;   // 16
constexpr int CT_ = 64;        // chunk length
constexpr int NC_ = L_ / CT_;  // 16 chunks

typedef __attribute__((ext_vector_type(8))) short bf16x8;
typedef __attribute__((ext_vector_type(4))) float f32x4;

__device__ __forceinline__ unsigned short f2bf(float f) {
  union { float f; unsigned int u; } v; v.f = f;
  const unsigned int u = v.u;
  return (unsigned short)((u + 0x7FFFu + ((u >> 16) & 1u)) >> 16);  // RNE
}
__device__ __forceinline__ float bf2f(unsigned short u) {
  union { unsigned int u; float f; } v; v.u = ((unsigned int)u) << 16;
  return v.f;
}

// Swizzled ushort index for a [64][64] bf16 LDS tile: conflict-free b128 reads.
__device__ __forceinline__ int sw(int row, int col) {
  return row * 64 + (col ^ ((row & 7) << 3));
}

// ---------------------------------------------------------------------------
// Fused projection GEMMs, 64x64 tile, BK=64, 768 blocks = 3/CU (z = 0:Q,
// 1:K, 2:V): out = sigmoid?(A @ W + b) stored BF16 permuted to [B,H,L,Dh];
// z<2 also writes per-(chunk,head) column sums of ROUNDED values.
// ---------------------------------------------------------------------------
__global__ __launch_bounds__(256) void proj3_k(const float* __restrict__ Qin,
                                               const float* __restrict__ Kin,
                                               const float* __restrict__ Vin,
                                               const float* __restrict__ Wq,
                                               const float* __restrict__ bq,
                                               const float* __restrict__ Wk,
                                               const float* __restrict__ bk,
                                               const float* __restrict__ Wv,
                                               const float* __restrict__ bv,
                                               unsigned short* __restrict__ Qb,
                                               unsigned short* __restrict__ Kb,
                                               unsigned short* __restrict__ Vb,
                                               float* __restrict__ sumQ,
                                               float* __restrict__ sumK) {
  const int z = blockIdx.z;
  const float* A    = (z == 0) ? Qin : (z == 1) ? Kin : Vin;
  const float* W    = (z == 0) ? Wq  : (z == 1) ? Wk  : Wv;
  const float* bias = (z == 0) ? bq  : (z == 1) ? bk  : bv;
  unsigned short* out = (z == 0) ? Qb : (z == 1) ? Kb : Vb;
  float* csum       = (z == 0) ? sumQ : (z == 1) ? sumK : nullptr;
  const bool sig = (z < 2);

  __shared__ __align__(16) short Als[64 * 72];  // [row][k0..64], pad 72
  __shared__ __align__(16) short Bls[64 * 72];  // [col][k0..64]
  const int tid = threadIdx.x;
  const int m0 = blockIdx.x * 64, n0 = blockIdx.y * 64;
  const int arow = tid >> 2, ak0 = (tid & 3) << 4;  // 16 k-contig per thread
  const int bcol = tid & 63, bk0 = (tid >> 6) << 4; // 16 k-strided per thread
  const int lane = tid & 63, wid = tid >> 6;
  const int wr = wid >> 1, wc = wid & 1;
  const int lrow = lane & 15, lk = (lane >> 4) << 3;

  f32x4 acc[2][2] = {{{0.f, 0.f, 0.f, 0.f}, {0.f, 0.f, 0.f, 0.f}},
                     {{0.f, 0.f, 0.f, 0.f}, {0.f, 0.f, 0.f, 0.f}}};
  float ra[16], rb[16];

  auto loadAB = [&](int kt) {
#pragma unroll
    for (int j = 0; j < 4; ++j) {
      const float4 f = *(const float4*)&A[(size_t)(m0 + arow) * D_ + kt + ak0 + 4 * j];
      ra[4 * j + 0] = f.x; ra[4 * j + 1] = f.y; ra[4 * j + 2] = f.z; ra[4 * j + 3] = f.w;
    }
    const float* gw = &W[(size_t)(kt + bk0) * D_ + n0 + bcol];
#pragma unroll
    for (int j = 0; j < 16; ++j) rb[j] = gw[(size_t)j * D_];
  };
  auto writeLDS = [&]() {
    bf16x8 pa0, pa1, pb0, pb1;
#pragma unroll
    for (int j = 0; j < 8; ++j) {
      pa0[j] = (short)f2bf(ra[j]);
      pa1[j] = (short)f2bf(ra[j + 8]);
      pb0[j] = (short)f2bf(rb[j]);
      pb1[j] = (short)f2bf(rb[j + 8]);
    }
    *(bf16x8*)&Als[arow * 72 + ak0] = pa0;
    *(bf16x8*)&Als[arow * 72 + ak0 + 8] = pa1;
    *(bf16x8*)&Bls[bcol * 72 + bk0] = pb0;
    *(bf16x8*)&Bls[bcol * 72 + bk0 + 8] = pb1;
  };
  auto compute = [&]() {
#pragma unroll
    for (int ks = 0; ks < 2; ++ks) {
      const int ko = ks * 32 + lk;
      bf16x8 a0 = *(const bf16x8*)&Als[(wr * 32 + lrow) * 72 + ko];
      bf16x8 a1 = *(const bf16x8*)&Als[(wr * 32 + 16 + lrow) * 72 + ko];
      bf16x8 b0 = *(const bf16x8*)&Bls[(wc * 32 + lrow) * 72 + ko];
      bf16x8 b1 = *(const bf16x8*)&Bls[(wc * 32 + 16 + lrow) * 72 + ko];
      acc[0][0] = __builtin_amdgcn_mfma_f32_16x16x32_bf16(a0, b0, acc[0][0], 0, 0, 0);
      acc[0][1] = __builtin_amdgcn_mfma_f32_16x16x32_bf16(a0, b1, acc[0][1], 0, 0, 0);
      acc[1][0] = __builtin_amdgcn_mfma_f32_16x16x32_bf16(a1, b0, acc[1][0], 0, 0, 0);
      acc[1][1] = __builtin_amdgcn_mfma_f32_16x16x32_bf16(a1, b1, acc[1][1], 0, 0, 0);
    }
  };

  loadAB(0);
  writeLDS();
  for (int kt = 64; kt < D_; kt += 64) {
    loadAB(kt);       // register prefetch of next K-tile
    __syncthreads();
    compute();
    __syncthreads();
    writeLDS();
  }
  __syncthreads();
  compute();

  const int b = m0 >> 10, h = n0 >> 6;
  float psum[2] = {0.f, 0.f};
#pragma unroll
  for (int j = 0; j < 2; ++j) {
    const int col = n0 + wc * 32 + j * 16 + lrow;
    const float bv4 = bias[col];
    const int dh = col & 63;
#pragma unroll
    for (int i = 0; i < 2; ++i) {
#pragma unroll
      for (int r = 0; r < 4; ++r) {
        const int row = m0 + wr * 32 + i * 16 + (lane >> 4) * 4 + r;
        float x = acc[i][j][r] + bv4;
        if (sig) x = 1.0f / (1.0f + expf(-x));
        const unsigned short ub = f2bf(x);
        const int l = row & (L_ - 1);
        out[(((size_t)(b * H_ + h)) * L_ + l) * DH_ + dh] = ub;
        psum[j] += bf2f(ub);  // sum the ROUNDED value: exact decomposition
      }
    }
  }
  if (csum) {
    float* sumS = (float*)Als;
#pragma unroll
    for (int j = 0; j < 2; ++j) {
      psum[j] += __shfl_xor(psum[j], 16);
      psum[j] += __shfl_xor(psum[j], 32);
      if ((lane >> 4) == 0) sumS[wr * 64 + wc * 32 + j * 16 + lrow] = psum[j];
    }
    __syncthreads();
    if (tid < 64) {
      const int c = (m0 & (L_ - 1)) >> 6;
      const int bc = (b * H_ + h) * NC_ + c;
      csum[bc * DH_ + tid] = sumS[tid] + sumS[64 + tid];
    }
  }
}

// ---------------------------------------------------------------------------
// Flow phase 1: 1024 thr = 16 waves, each scanning 4 d-columns (4x shorter
// serial chain, 16 waves/CU of latency hiding). bf16 q/k in, fp32 scans.
// ---------------------------------------------------------------------------
__global__ __launch_bounds__(1024) void flow_phase1_k(const unsigned short* __restrict__ Qb,
                                                      const unsigned short* __restrict__ Kb,
                                                      const float* __restrict__ sumQ,
                                                      const float* __restrict__ sumK,
                                                      float* __restrict__ qscale,
                                                      float* __restrict__ si_a,
                                                      float* __restrict__ so_a,
                                                      float* __restrict__ sumQSI,
                                                      float* __restrict__ sumKSO) {
  const int bc = blockIdx.x, bh = bc >> 4, c = bc & (NC_ - 1);
  const int g = bc * CT_;
  const int tid = threadIdx.x, lane = tid & 63, w = tid >> 6;  // w in [0,16)
  __shared__ float qS[64][65], kS[64][65];
  __shared__ float pqS[64], pkS[64];
  __shared__ float aS[16][64], bS[16][64];
  __shared__ float siS[64], soS[64];
  if (tid < 512) {
    const int row = tid >> 3, d0 = (tid & 7) << 3;
    const bf16x8 qv = *(const bf16x8*)&Qb[(size_t)g * DH_ + tid * 8];
    const bf16x8 kv = *(const bf16x8*)&Kb[(size_t)g * DH_ + tid * 8];
#pragma unroll
    for (int j = 0; j < 8; ++j) {
      qS[row][d0 + j] = bf2f((unsigned short)qv[j]);
      kS[row][d0 + j] = bf2f((unsigned short)kv[j]);
    }
  } else if (tid < 576) {
    const int d = tid - 512;
    float pq = 0.f, pk = 0.f;
    for (int cc = 0; cc < c; ++cc) {
      pq += sumQ[(bh * NC_ + cc) * DH_ + d];
      pk += sumK[(bh * NC_ + cc) * DH_ + d];
    }
    pqS[d] = pq; pkS[d] = pk;
  }
  __syncthreads();
  float ap = 0.f, bp = 0.f;
#pragma unroll
  for (int dd = 0; dd < 4; ++dd) {
    const int d = w * 4 + dd;
    const float qv = qS[lane][d];
    const float kv = kS[lane][d];
    float ck = kv, cq = qv;
#pragma unroll
    for (int off = 1; off < 64; off <<= 1) {
      const float t1 = __shfl_up(ck, off);
      const float t2 = __shfl_up(cq, off);
      ck += (lane >= off) ? t1 : 0.f;
      cq += (lane >= off) ? t2 : 0.f;
    }
    ck += pkS[d];
    cq += pqS[d];
    ap += (qv + EPSF) * (ck + EPSF);
    bp += (kv + EPSF) * (cq + EPSF);
  }
  aS[w][lane] = ap; bS[w][lane] = bp;
  __syncthreads();
  if (tid < 64) {
    float a = 0.f, b = 0.f;
#pragma unroll
    for (int ww = 0; ww < 16; ++ww) { a += aS[ww][tid]; b += bS[ww][tid]; }
    const float normal = (float)(c * CT_ + tid + 1);
    const float si = normal / a, so = normal / b;
    qscale[g + tid] = 1.0f / a;
    si_a[g + tid] = si;
    so_a[g + tid] = so;
    siS[tid] = si; soS[tid] = so;
  }
  __syncthreads();
  float sq = 0.f, sk = 0.f;
#pragma unroll
  for (int li = 0; li < 4; ++li) {
    const int l = w * 4 + li;
    sq += qS[l][lane] * siS[l];
    sk += kS[l][lane] * soS[l];
  }
  aS[w][lane] = sq; bS[w][lane] = sk;
  __syncthreads();
  if (tid < 64) {
    float s1 = 0.f, s2 = 0.f;
#pragma unroll
    for (int ww = 0; ww < 16; ++ww) { s1 += aS[ww][tid]; s2 += bS[ww][tid]; }
    sumQSI[bc * DH_ + tid] = s1;
    sumKSO[bc * DH_ + tid] = s2;
  }
}

// ---------------------------------------------------------------------------
// Flow phase 2: 1024 thr = 16 waves, 4 d-columns per wave. Outputs salloc,
// e, chunk sumE.
// ---------------------------------------------------------------------------
__global__ __launch_bounds__(1024) void flow_phase2_k(const unsigned short* __restrict__ Qb,
                                                      const unsigned short* __restrict__ Kb,
                                                      const float* __restrict__ sumQSI,
                                                      const float* __restrict__ sumKSO,
                                                      const float* __restrict__ si_a,
                                                      const float* __restrict__ so_a,
                                                      float* __restrict__ salloc,
                                                      float* __restrict__ e_a,
                                                      float* __restrict__ sumE) {
  const int bc = blockIdx.x, bh = bc >> 4, c = bc & (NC_ - 1);
  const int g = bc * CT_;
  const int tid = threadIdx.x, lane = tid & 63, w = tid >> 6;
  __shared__ float qS[64][65], kS[64][65];
  __shared__ float pqS[64], pkS[64];
  __shared__ float aS[16][64], bS[16][64];
  if (tid < 512) {
    const int row = tid >> 3, d0 = (tid & 7) << 3;
    const bf16x8 qv = *(const bf16x8*)&Qb[(size_t)g * DH_ + tid * 8];
    const bf16x8 kv = *(const bf16x8*)&Kb[(size_t)g * DH_ + tid * 8];
#pragma unroll
    for (int j = 0; j < 8; ++j) {
      qS[row][d0 + j] = bf2f((unsigned short)qv[j]);
      kS[row][d0 + j] = bf2f((unsigned short)kv[j]);
    }
  } else if (tid < 576) {
    const int d = tid - 512;
    float pq = 0.f, pk = 0.f;
    for (int cc = 0; cc < c; ++cc) {
      pq += sumQSI[(bh * NC_ + cc) * DH_ + d];
      pk += sumKSO[(bh * NC_ + cc) * DH_ + d];
    }
    pqS[d] = pq; pkS[d] = pk;
  }
  __syncthreads();
  const float si = si_a[g + lane];
  const float so = so_a[g + lane];
  float c1p = 0.f, c2p = 0.f;
#pragma unroll
  for (int dd = 0; dd < 4; ++dd) {
    const int d = w * 4 + dd;
    const float qv = qS[lane][d];
    const float kv = kS[lane][d];
    float ckso = kv * so, cqsi = qv * si;
#pragma unroll
    for (int off = 1; off < 64; off <<= 1) {
      const float t1 = __shfl_up(ckso, off);
      const float t2 = __shfl_up(cqsi, off);
      ckso += (lane >= off) ? t1 : 0.f;
      cqsi += (lane >= off) ? t2 : 0.f;
    }
    ckso += pkS[d];
    cqsi += pqS[d];
    c1p += (qv + EPSF) * (ckso + EPSF);
    c2p += (kv + EPSF) * (cqsi + EPSF);
  }
  aS[w][lane] = c1p; bS[w][lane] = c2p;
  __syncthreads();
  if (tid < 64) {
    float c1 = 0.f, c2 = 0.f;
#pragma unroll
    for (int ww = 0; ww < 16; ++ww) { c1 += aS[ww][tid]; c2 += bS[ww][tid]; }
    const float normal = (float)(c * CT_ + tid + 1);
    const float cs_sink = c1 / normal;
    salloc[g + tid] = 1.0f / (1.0f + expf(-cs_sink));
    float cs_src = c2 / normal;
    cs_src = fminf(1.0f, fmaxf(-1.0f, cs_src));
    const float e = expf(cs_src);
    e_a[g + tid] = e;
    float tot = e;
#pragma unroll
    for (int off = 32; off; off >>= 1) tot += __shfl_xor(tot, off);
    if (tid == 0) sumE[bc] = tot;
  }
}

// ---------------------------------------------------------------------------
// Fused: source_competition (inline prefix of sumE) + MFMA chunk-KV:
// KV[bc][d][m] = sum_l k[l,d] * (v[l,m]*comp[l])  ==  k^T @ v'.  (raw, not
// prefixed — attn does the prefix inline.)
// ---------------------------------------------------------------------------
__global__ __launch_bounds__(256) void flow_ckv_k(const unsigned short* __restrict__ K16,
                                                  const unsigned short* __restrict__ V16,
                                                  const float* __restrict__ e_a,
                                                  const float* __restrict__ sumE,
                                                  float* __restrict__ comp,
                                                  float* __restrict__ KV) {
  const int bc = blockIdx.x, bh = bc >> 4, c = bc & (NC_ - 1);
  const int g = bc * CT_;
  const int tid = threadIdx.x;
  __shared__ float compS[CT_];
  __shared__ __align__(16) unsigned short kT16[64 * 64];  // [d][l]
  __shared__ __align__(16) unsigned short vT16[64 * 64];  // [m][l] = v'[l][m]
  if (tid < 64) {
    const int lane = tid;
    const float e = e_a[g + lane];
    float se = (lane < c) ? sumE[bh * NC_ + lane] : 0.f;
#pragma unroll
    for (int off = 32; off; off >>= 1) se += __shfl_xor(se, off);
    float s = e;
#pragma unroll
    for (int off = 1; off < 64; off <<= 1) {
      const float t = __shfl_up(s, off);
      s += (lane >= off) ? t : 0.f;
    }
    const float cf = e / (se + s) * (float)(c * CT_ + lane + 1);
    compS[lane] = cf;
    comp[g + lane] = cf;
  }
  __syncthreads();
#pragma unroll
  for (int it = 0; it < 2; ++it) {
    const int i8 = it * 256 + tid;
    const int l = i8 >> 3, d0 = (i8 & 7) << 3;
    const bf16x8 kv = *(const bf16x8*)&K16[(size_t)g * DH_ + i8 * 8];
    const bf16x8 vv = *(const bf16x8*)&V16[(size_t)g * DH_ + i8 * 8];
    const float cl = compS[l];
#pragma unroll
    for (int j = 0; j < 8; ++j) {
      kT16[sw(d0 + j, l)] = (unsigned short)kv[j];
      vT16[sw(d0 + j, l)] = f2bf(bf2f((unsigned short)vv[j]) * cl);
    }
  }
  __syncthreads();
  const int lane = tid & 63, w = tid >> 6;
  const int fr = lane & 15, fk = (lane >> 4) << 3;
  f32x4 acc[4] = {{0.f, 0.f, 0.f, 0.f}, {0.f, 0.f, 0.f, 0.f},
                  {0.f, 0.f, 0.f, 0.f}, {0.f, 0.f, 0.f, 0.f}};
  const bf16x8 a0 = *(const bf16x8*)&kT16[sw(w * 16 + fr, fk)];
  const bf16x8 a1 = *(const bf16x8*)&kT16[sw(w * 16 + fr, fk + 32)];
#pragma unroll
  for (int cb = 0; cb < 4; ++cb) {
    const bf16x8 b0 = *(const bf16x8*)&vT16[sw(cb * 16 + fr, fk)];
    const bf16x8 b1 = *(const bf16x8*)&vT16[sw(cb * 16 + fr, fk + 32)];
    acc[cb] = __builtin_amdgcn_mfma_f32_16x16x32_bf16(a0, b0, acc[cb], 0, 0, 0);
    acc[cb] = __builtin_amdgcn_mfma_f32_16x16x32_bf16(a1, b1, acc[cb], 0, 0, 0);
  }
  float* outp = KV + (size_t)bc * DH_ * DH_;
#pragma unroll
  for (int r = 0; r < 4; ++r) {
    const int d = w * 16 + (lane >> 4) * 4 + r;
#pragma unroll
    for (int cb = 0; cb < 4; ++cb) outp[d * DH_ + cb * 16 + fr] = acc[cb][r];
  }
}

// ---------------------------------------------------------------------------
// MFMA attention with inline KV prefix (fully-unrolled masked sum over raw
// chunk KVs — independent pipelined loads, L2-resident).
// X = (qp @ KVp + tril(qp k^T) @ v') * salloc, bf16 out.
// ---------------------------------------------------------------------------
__global__ __launch_bounds__(256) void attn_k(const unsigned short* __restrict__ Q16,
                                              const unsigned short* __restrict__ K16,
                                              const unsigned short* __restrict__ V16,
                                              const float* __restrict__ KVraw,
                                              const float* __restrict__ qscale,
                                              const float* __restrict__ salloc,
                                              const float* __restrict__ comp,
                                              unsigned short* __restrict__ X) {
  const int bc = blockIdx.x;
  const int bh = bc >> 4, c = bc & (NC_ - 1);
  const int bb = bh >> 3, hh = bh & (H_ - 1);
  const int g = bc * CT_;
  __shared__ __align__(16) unsigned short qp16[64 * 64];  // [l][d]
  __shared__ __align__(16) unsigned short k16[64 * 64];   // [j][d]
  __shared__ __align__(16) unsigned short vT16[64 * 64];  // [m][j] = v'[j][m]
  __shared__ __align__(16) unsigned short kvT16[64 * 64]; // [m][d] = KVp[d][m]
  __shared__ __align__(16) unsigned short S16[64 * 64];   // [l][j] masked scores
  const int tid = threadIdx.x;
#pragma unroll
  for (int it = 0; it < 2; ++it) {
    const int i8 = it * 256 + tid;
    const int r = i8 >> 3, d0 = (i8 & 7) << 3;
    const bf16x8 qv = *(const bf16x8*)&Q16[(size_t)g * DH_ + i8 * 8];
    const bf16x8 kv = *(const bf16x8*)&K16[(size_t)g * DH_ + i8 * 8];
    const bf16x8 vv = *(const bf16x8*)&V16[(size_t)g * DH_ + i8 * 8];
    const float qs = qscale[g + r];
    const float cl = comp[g + r];
    bf16x8 pq;
#pragma unroll
    for (int j = 0; j < 8; ++j) pq[j] = (short)f2bf(bf2f((unsigned short)qv[j]) * qs);
    *(bf16x8*)&qp16[sw(r, d0)] = pq;
    *(bf16x8*)&k16[sw(r, d0)] = kv;
#pragma unroll
    for (int j = 0; j < 8; ++j)
      vT16[sw(d0 + j, r)] = f2bf(bf2f((unsigned short)vv[j]) * cl);
  }
  // kvT = transposed exclusive prefix: unrolled masked sum over raw chunk KVs
  {
    const float* kvbh = KVraw + (size_t)bh * NC_ * DH_ * DH_;
    for (int i4 = tid; i4 < DH_ * DH_ / 4; i4 += 256) {
      const int d = i4 >> 4, mg = (i4 & 15) << 2;
      float s0 = 0.f, s1 = 0.f, s2 = 0.f, s3 = 0.f;
#pragma unroll
      for (int cc = 0; cc < NC_; ++cc) {
        const float4 t = *(const float4*)&kvbh[(size_t)cc * (DH_ * DH_) + d * DH_ + mg];
        const float msk = (cc < c) ? 1.f : 0.f;
        s0 += t.x * msk; s1 += t.y * msk; s2 += t.z * msk; s3 += t.w * msk;
      }
      kvT16[sw(mg + 0, d)] = f2bf(s0);
      kvT16[sw(mg + 1, d)] = f2bf(s1);
      kvT16[sw(mg + 2, d)] = f2bf(s2);
      kvT16[sw(mg + 3, d)] = f2bf(s3);
    }
  }
  __syncthreads();

  const int lane = tid & 63, w = tid >> 6;
  const int fr = lane & 15, fk = (lane >> 4) << 3;
  const int arow = w * 16 + fr;
  f32x4 accX[4] = {{0.f, 0.f, 0.f, 0.f}, {0.f, 0.f, 0.f, 0.f},
                   {0.f, 0.f, 0.f, 0.f}, {0.f, 0.f, 0.f, 0.f}};
  f32x4 accS[4] = {{0.f, 0.f, 0.f, 0.f}, {0.f, 0.f, 0.f, 0.f},
                   {0.f, 0.f, 0.f, 0.f}, {0.f, 0.f, 0.f, 0.f}};

  const bf16x8 aq0 = *(const bf16x8*)&qp16[sw(arow, fk)];
  const bf16x8 aq1 = *(const bf16x8*)&qp16[sw(arow, fk + 32)];
#pragma unroll
  for (int cb = 0; cb < 4; ++cb) {
    const int bcol = cb * 16 + fr;
    const bf16x8 bv0 = *(const bf16x8*)&kvT16[sw(bcol, fk)];
    const bf16x8 bv1 = *(const bf16x8*)&kvT16[sw(bcol, fk + 32)];
    accX[cb] = __builtin_amdgcn_mfma_f32_16x16x32_bf16(aq0, bv0, accX[cb], 0, 0, 0);
    accX[cb] = __builtin_amdgcn_mfma_f32_16x16x32_bf16(aq1, bv1, accX[cb], 0, 0, 0);
    const bf16x8 bk0 = *(const bf16x8*)&k16[sw(bcol, fk)];
    const bf16x8 bk1 = *(const bf16x8*)&k16[sw(bcol, fk + 32)];
    accS[cb] = __builtin_amdgcn_mfma_f32_16x16x32_bf16(aq0, bk0, accS[cb], 0, 0, 0);
    accS[cb] = __builtin_amdgcn_mfma_f32_16x16x32_bf16(aq1, bk1, accS[cb], 0, 0, 0);
  }
#pragma unroll
  for (int cb = 0; cb < 4; ++cb) {
#pragma unroll
    for (int r = 0; r < 4; ++r) {
      const int l = w * 16 + (lane >> 4) * 4 + r;
      const int j = cb * 16 + fr;
      S16[sw(l, j)] = (j <= l) ? f2bf(accS[cb][r]) : (unsigned short)0;
    }
  }
  __syncthreads();
  const bf16x8 as0 = *(const bf16x8*)&S16[sw(arow, fk)];
  const bf16x8 as1 = *(const bf16x8*)&S16[sw(arow, fk + 32)];
#pragma unroll
  for (int cb = 0; cb < 4; ++cb) {
    const int bcol = cb * 16 + fr;
    const bf16x8 bv0 = *(const bf16x8*)&vT16[sw(bcol, fk)];
    const bf16x8 bv1 = *(const bf16x8*)&vT16[sw(bcol, fk + 32)];
    accX[cb] = __builtin_amdgcn_mfma_f32_16x16x32_bf16(as0, bv0, accX[cb], 0, 0, 0);
    accX[cb] = __builtin_amdgcn_mfma_f32_16x16x32_bf16(as1, bv1, accX[cb], 0, 0, 0);
  }
#pragma unroll
  for (int r = 0; r < 4; ++r) {
    const int l = w * 16 + (lane >> 4) * 4 + r;
    const float sal = salloc[g + l];
    const size_t rowbase = ((size_t)(bb * L_ + c * CT_ + l)) * D_ + hh * DH_;
#pragma unroll
    for (int cb = 0; cb < 4; ++cb) {
      const int m = cb * 16 + fr;
      X[rowbase + m] = f2bf(accX[cb][r] * sal);
    }
  }
}

// ---------------------------------------------------------------------------
// Output GEMM: d_out = X(bf16) @ Wo + bo. 64x64 tile, BK=64, 256 blocks.
// ---------------------------------------------------------------------------
__global__ __launch_bounds__(256) void gemm_out_k(const unsigned short* __restrict__ A,
                                                  const float* __restrict__ W,
                                                  const float* __restrict__ bias,
                                                  float* __restrict__ out) {
  __shared__ __align__(16) short Als[64 * 72];
  __shared__ __align__(16) short Bls[64 * 72];
  const int tid = threadIdx.x;
  const int m0 = blockIdx.x * 64, n0 = blockIdx.y * 64;
  const int arow = tid >> 2, ak0 = (tid & 3) << 4;   // 16 bf16, contiguous
  const int bcol = tid & 63, bk0 = (tid >> 6) << 4;  // 16 k-strided floats
  const int lane = tid & 63, wid = tid >> 6;
  const int wr = wid >> 1, wc = wid & 1;
  const int lrow = lane & 15, lk = (lane >> 4) << 3;

  f32x4 acc[2][2] = {{{0.f, 0.f, 0.f, 0.f}, {0.f, 0.f, 0.f, 0.f}},
                     {{0.f, 0.f, 0.f, 0.f}, {0.f, 0.f, 0.f, 0.f}}};
  bf16x8 pa0, pa1;
  float rb[16];
  auto loadAB = [&](int kt) {
    pa0 = *(const bf16x8*)&A[(size_t)(m0 + arow) * D_ + kt + ak0];
    pa1 = *(const bf16x8*)&A[(size_t)(m0 + arow) * D_ + kt + ak0 + 8];
    const float* gw = &W[(size_t)(kt + bk0) * D_ + n0 + bcol];
#pragma unroll
    for (int j = 0; j < 16; ++j) rb[j] = gw[(size_t)j * D_];
  };
  auto writeLDS = [&]() {
    bf16x8 pb0, pb1;
#pragma unroll
    for (int j = 0; j < 8; ++j) {
      pb0[j] = (short)f2bf(rb[j]);
      pb1[j] = (short)f2bf(rb[j + 8]);
    }
    *(bf16x8*)&Als[arow * 72 + ak0] = pa0;
    *(bf16x8*)&Als[arow * 72 + ak0 + 8] = pa1;
    *(bf16x8*)&Bls[bcol * 72 + bk0] = pb0;
    *(bf16x8*)&Bls[bcol * 72 + bk0 + 8] = pb1;
  };
  auto compute = [&]() {
#pragma unroll
    for (int ks = 0; ks < 2; ++ks) {
      const int ko = ks * 32 + lk;
      bf16x8 a0 = *(const bf16x8*)&Als[(wr * 32 + lrow) * 72 + ko];
      bf16x8 a1 = *(const bf16x8*)&Als[(wr * 32 + 16 + lrow) * 72 + ko];
      bf16x8 b0 = *(const bf16x8*)&Bls[(wc * 32 + lrow) * 72 + ko];
      bf16x8 b1 = *(const bf16x8*)&Bls[(wc * 32 + 16 + lrow) * 72 + ko];
      acc[0][0] = __builtin_amdgcn_mfma_f32_16x16x32_bf16(a0, b0, acc[0][0], 0, 0, 0);
      acc[0][1] = __builtin_amdgcn_mfma_f32_16x16x32_bf16(a0, b1, acc[0][1], 0, 0, 0);
      acc[1][0] = __builtin_amdgcn_mfma_f32_16x16x32_bf16(a1, b0, acc[1][0], 0, 0, 0);
      acc[1][1] = __builtin_amdgcn_mfma_f32_16x16x32_bf16(a1, b1, acc[1][1], 0, 0, 0);
    }
  };

  loadAB(0);
  writeLDS();
  for (int kt = 64; kt < D_; kt += 64) {
    loadAB(kt);
    __syncthreads();
    compute();
    __syncthreads();
    writeLDS();
  }
  __syncthreads();
  compute();

#pragma unroll
  for (int j = 0; j < 2; ++j) {
    const int col = n0 + wc * 32 + j * 16 + lrow;
    const float bv4 = bias[col];
#pragma unroll
    for (int i = 0; i < 2; ++i) {
#pragma unroll
      for (int r = 0; r < 4; ++r) {
        const int row = m0 + wr * 32 + i * 16 + (lane >> 4) * 4 + r;
        out[(size_t)row * D_ + col] = acc[i][j][r] + bv4;
      }
    }
  }
}

// ---------------------------------------------------------------------------
extern "C" void kernel_launch(void* const* d_in, const int* in_sizes, int n_in,
                              void* d_out, int out_size, void* d_ws, size_t ws_size,
                              hipStream_t stream) {
  (void)in_sizes; (void)n_in; (void)out_size; (void)ws_size;
  const float* queries = (const float*)d_in[0];
  const float* keys    = (const float*)d_in[1];
  const float* values  = (const float*)d_in[2];
  const float* Wq = (const float*)d_in[3];
  const float* bq = (const float*)d_in[4];
  const float* Wk = (const float*)d_in[5];
  const float* bk = (const float*)d_in[6];
  const float* Wv = (const float*)d_in[7];
  const float* bv = (const float*)d_in[8];
  const float* Wo = (const float*)d_in[9];
  const float* bo = (const float*)d_in[10];

  const size_t seg = (size_t)BH_ * L_ * DH_;  // 1,048,576 elements
  unsigned short* Qb = (unsigned short*)d_ws;          // bf16 [BH,L,Dh]
  unsigned short* Kb = Qb + seg;
  unsigned short* Vb = Kb + seg;
  float* KVb = (float*)(Vb + seg);                      // [BH, NC, 64, 64] raw
  float* p   = KVb + (size_t)BH_ * NC_ * DH_ * DH_;
  float* qscale = p; p += BH_ * L_;
  float* salloc = p; p += BH_ * L_;
  float* comp   = p; p += BH_ * L_;
  float* si_a   = p; p += BH_ * L_;
  float* so_a   = p; p += BH_ * L_;
  float* e_a    = p; p += BH_ * L_;
  float* sumQ   = p; p += BH_ * NC_ * DH_;
  float* sumK   = p; p += BH_ * NC_ * DH_;
  float* sumQSI = p; p += BH_ * NC_ * DH_;
  float* sumKSO = p; p += BH_ * NC_ * DH_;
  float* sumE   = p; p += BH_ * NC_;
  unsigned short* Xb16 = (unsigned short*)p;            // [BL, D] bf16

  proj3_k<<<dim3(BL_ / 64, D_ / 64, 3), 256, 0, stream>>>(
      queries, keys, values, Wq, bq, Wk, bk, Wv, bv, Qb, Kb, Vb, sumQ, sumK);
  flow_phase1_k<<<BH_ * NC_, 1024, 0, stream>>>(Qb, Kb, sumQ, sumK,
                                                qscale, si_a, so_a, sumQSI, sumKSO);
  flow_phase2_k<<<BH_ * NC_, 1024, 0, stream>>>(Qb, Kb, sumQSI, sumKSO, si_a, so_a,
                                                salloc, e_a, sumE);
  flow_ckv_k<<<BH_ * NC_, 256, 0, stream>>>(Kb, Vb, e_a, sumE, comp, KVb);
  attn_k<<<BH_ * NC_, 256, 0, stream>>>(Qb, Kb, Vb, KVb, qscale, salloc, comp, Xb16);
  gemm_out_k<<<dim3(BL_ / 64, D_ / 64), 256, 0, stream>>>(Xb16, Wo, bo, (float*)d_out);
}

// Round 13
// 56.418 us; speedup vs baseline: 1.1584x; 1.0247x over previous
//
#include <hip/hip_runtime.h>
#include <math.h>

#define EPSF 1e-6f

constexpr int B_  = 2;
constexpr int L_  = 1024;
constexpr int D_  = 512;
constexpr int H_  = 8;
constexpr int DH_ = 64;
constexpr int BL_ = B_ * L_;   // 2048
constexpr int BH_ = B_ * H_;   // 16
constexpr int CT_ = 64;        // chunk length
constexpr int NC_ = L_ / CT_;  // 16 chunks

typedef __attribute__((ext_vector_type(8))) short bf16x8;
typedef __attribute__((ext_vector_type(4))) float f32x4;

__device__ __forceinline__ unsigned short f2bf(float f) {
  union { float f; unsigned int u; } v; v.f = f;
  const unsigned int u = v.u;
  return (unsigned short)((u + 0x7FFFu + ((u >> 16) & 1u)) >> 16);  // RNE
}
__device__ __forceinline__ float bf2f(unsigned short u) {
  union { unsigned int u; float f; } v; v.u = ((unsigned int)u) << 16;
  return v.f;
}

// Swizzled ushort index for a [64][64] bf16 LDS tile: conflict-free b128 reads.
__device__ __forceinline__ int sw(int row, int col) {
  return row * 64 + (col ^ ((row & 7) << 3));
}

// ---------------------------------------------------------------------------
// Fused projection GEMMs, 64x64 tile, BK=64, 768 blocks = 3/CU (z = 0:Q,
// 1:K, 2:V): out = sigmoid?(A @ W + b) stored BF16 permuted to [B,H,L,Dh];
// z<2 also writes per-(chunk,head) column sums of ROUNDED values.
// ---------------------------------------------------------------------------
__global__ __launch_bounds__(256) void proj3_k(const float* __restrict__ Qin,
                                               const float* __restrict__ Kin,
                                               const float* __restrict__ Vin,
                                               const float* __restrict__ Wq,
                                               const float* __restrict__ bq,
                                               const float* __restrict__ Wk,
                                               const float* __restrict__ bk,
                                               const float* __restrict__ Wv,
                                               const float* __restrict__ bv,
                                               unsigned short* __restrict__ Qb,
                                               unsigned short* __restrict__ Kb,
                                               unsigned short* __restrict__ Vb,
                                               float* __restrict__ sumQ,
                                               float* __restrict__ sumK) {
  const int z = blockIdx.z;
  const float* A    = (z == 0) ? Qin : (z == 1) ? Kin : Vin;
  const float* W    = (z == 0) ? Wq  : (z == 1) ? Wk  : Wv;
  const float* bias = (z == 0) ? bq  : (z == 1) ? bk  : bv;
  unsigned short* out = (z == 0) ? Qb : (z == 1) ? Kb : Vb;
  float* csum       = (z == 0) ? sumQ : (z == 1) ? sumK : nullptr;
  const bool sig = (z < 2);

  __shared__ __align__(16) short Als[64 * 72];  // [row][k0..64], pad 72
  __shared__ __align__(16) short Bls[64 * 72];  // [col][k0..64]
  const int tid = threadIdx.x;
  const int m0 = blockIdx.x * 64, n0 = blockIdx.y * 64;
  const int arow = tid >> 2, ak0 = (tid & 3) << 4;  // 16 k-contig per thread
  const int bcol = tid & 63, bk0 = (tid >> 6) << 4; // 16 k-strided per thread
  const int lane = tid & 63, wid = tid >> 6;
  const int wr = wid >> 1, wc = wid & 1;
  const int lrow = lane & 15, lk = (lane >> 4) << 3;

  f32x4 acc[2][2] = {{{0.f, 0.f, 0.f, 0.f}, {0.f, 0.f, 0.f, 0.f}},
                     {{0.f, 0.f, 0.f, 0.f}, {0.f, 0.f, 0.f, 0.f}}};
  float ra[16], rb[16];

  auto loadAB = [&](int kt) {
#pragma unroll
    for (int j = 0; j < 4; ++j) {
      const float4 f = *(const float4*)&A[(size_t)(m0 + arow) * D_ + kt + ak0 + 4 * j];
      ra[4 * j + 0] = f.x; ra[4 * j + 1] = f.y; ra[4 * j + 2] = f.z; ra[4 * j + 3] = f.w;
    }
    const float* gw = &W[(size_t)(kt + bk0) * D_ + n0 + bcol];
#pragma unroll
    for (int j = 0; j < 16; ++j) rb[j] = gw[(size_t)j * D_];
  };
  auto writeLDS = [&]() {
    bf16x8 pa0, pa1, pb0, pb1;
#pragma unroll
    for (int j = 0; j < 8; ++j) {
      pa0[j] = (short)f2bf(ra[j]);
      pa1[j] = (short)f2bf(ra[j + 8]);
      pb0[j] = (short)f2bf(rb[j]);
      pb1[j] = (short)f2bf(rb[j + 8]);
    }
    *(bf16x8*)&Als[arow * 72 + ak0] = pa0;
    *(bf16x8*)&Als[arow * 72 + ak0 + 8] = pa1;
    *(bf16x8*)&Bls[bcol * 72 + bk0] = pb0;
    *(bf16x8*)&Bls[bcol * 72 + bk0 + 8] = pb1;
  };
  auto compute = [&]() {
#pragma unroll
    for (int ks = 0; ks < 2; ++ks) {
      const int ko = ks * 32 + lk;
      bf16x8 a0 = *(const bf16x8*)&Als[(wr * 32 + lrow) * 72 + ko];
      bf16x8 a1 = *(const bf16x8*)&Als[(wr * 32 + 16 + lrow) * 72 + ko];
      bf16x8 b0 = *(const bf16x8*)&Bls[(wc * 32 + lrow) * 72 + ko];
      bf16x8 b1 = *(const bf16x8*)&Bls[(wc * 32 + 16 + lrow) * 72 + ko];
      acc[0][0] = __builtin_amdgcn_mfma_f32_16x16x32_bf16(a0, b0, acc[0][0], 0, 0, 0);
      acc[0][1] = __builtin_amdgcn_mfma_f32_16x16x32_bf16(a0, b1, acc[0][1], 0, 0, 0);
      acc[1][0] = __builtin_amdgcn_mfma_f32_16x16x32_bf16(a1, b0, acc[1][0], 0, 0, 0);
      acc[1][1] = __builtin_amdgcn_mfma_f32_16x16x32_bf16(a1, b1, acc[1][1], 0, 0, 0);
    }
  };

  loadAB(0);
  writeLDS();
  for (int kt = 64; kt < D_; kt += 64) {
    loadAB(kt);       // register prefetch of next K-tile
    __syncthreads();
    compute();
    __syncthreads();
    writeLDS();
  }
  __syncthreads();
  compute();

  const int b = m0 >> 10, h = n0 >> 6;
  float psum[2] = {0.f, 0.f};
#pragma unroll
  for (int j = 0; j < 2; ++j) {
    const int col = n0 + wc * 32 + j * 16 + lrow;
    const float bv4 = bias[col];
    const int dh = col & 63;
#pragma unroll
    for (int i = 0; i < 2; ++i) {
#pragma unroll
      for (int r = 0; r < 4; ++r) {
        const int row = m0 + wr * 32 + i * 16 + (lane >> 4) * 4 + r;
        float x = acc[i][j][r] + bv4;
        if (sig) x = 1.0f / (1.0f + expf(-x));
        const unsigned short ub = f2bf(x);
        const int l = row & (L_ - 1);
        out[(((size_t)(b * H_ + h)) * L_ + l) * DH_ + dh] = ub;
        psum[j] += bf2f(ub);  // sum the ROUNDED value: exact decomposition
      }
    }
  }
  if (csum) {
    float* sumS = (float*)Als;
#pragma unroll
    for (int j = 0; j < 2; ++j) {
      psum[j] += __shfl_xor(psum[j], 16);
      psum[j] += __shfl_xor(psum[j], 32);
      if ((lane >> 4) == 0) sumS[wr * 64 + wc * 32 + j * 16 + lrow] = psum[j];
    }
    __syncthreads();
    if (tid < 64) {
      const int c = (m0 & (L_ - 1)) >> 6;
      const int bc = (b * H_ + h) * NC_ + c;
      csum[bc * DH_ + tid] = sumS[tid] + sumS[64 + tid];
    }
  }
}

// ---------------------------------------------------------------------------
// Flow phase 1: 1024 thr = 16 waves, each scanning 4 d-columns.
// ---------------------------------------------------------------------------
__global__ __launch_bounds__(1024) void flow_phase1_k(const unsigned short* __restrict__ Qb,
                                                      const unsigned short* __restrict__ Kb,
                                                      const float* __restrict__ sumQ,
                                                      const float* __restrict__ sumK,
                                                      float* __restrict__ qscale,
                                                      float* __restrict__ si_a,
                                                      float* __restrict__ so_a,
                                                      float* __restrict__ sumQSI,
                                                      float* __restrict__ sumKSO) {
  const int bc = blockIdx.x, bh = bc >> 4, c = bc & (NC_ - 1);
  const int g = bc * CT_;
  const int tid = threadIdx.x, lane = tid & 63, w = tid >> 6;  // w in [0,16)
  __shared__ float qS[64][65], kS[64][65];
  __shared__ float pqS[64], pkS[64];
  __shared__ float aS[16][64], bS[16][64];
  __shared__ float siS[64], soS[64];
  if (tid < 512) {
    const int row = tid >> 3, d0 = (tid & 7) << 3;
    const bf16x8 qv = *(const bf16x8*)&Qb[(size_t)g * DH_ + tid * 8];
    const bf16x8 kv = *(const bf16x8*)&Kb[(size_t)g * DH_ + tid * 8];
#pragma unroll
    for (int j = 0; j < 8; ++j) {
      qS[row][d0 + j] = bf2f((unsigned short)qv[j]);
      kS[row][d0 + j] = bf2f((unsigned short)kv[j]);
    }
  } else if (tid < 576) {
    const int d = tid - 512;
    float pq = 0.f, pk = 0.f;
    for (int cc = 0; cc < c; ++cc) {
      pq += sumQ[(bh * NC_ + cc) * DH_ + d];
      pk += sumK[(bh * NC_ + cc) * DH_ + d];
    }
    pqS[d] = pq; pkS[d] = pk;
  }
  __syncthreads();
  float ap = 0.f, bp = 0.f;
#pragma unroll
  for (int dd = 0; dd < 4; ++dd) {
    const int d = w * 4 + dd;
    const float qv = qS[lane][d];
    const float kv = kS[lane][d];
    float ck = kv, cq = qv;
#pragma unroll
    for (int off = 1; off < 64; off <<= 1) {
      const float t1 = __shfl_up(ck, off);
      const float t2 = __shfl_up(cq, off);
      ck += (lane >= off) ? t1 : 0.f;
      cq += (lane >= off) ? t2 : 0.f;
    }
    ck += pkS[d];
    cq += pqS[d];
    ap += (qv + EPSF) * (ck + EPSF);
    bp += (kv + EPSF) * (cq + EPSF);
  }
  aS[w][lane] = ap; bS[w][lane] = bp;
  __syncthreads();
  if (tid < 64) {
    float a = 0.f, b = 0.f;
#pragma unroll
    for (int ww = 0; ww < 16; ++ww) { a += aS[ww][tid]; b += bS[ww][tid]; }
    const float normal = (float)(c * CT_ + tid + 1);
    const float si = normal / a, so = normal / b;
    qscale[g + tid] = 1.0f / a;
    si_a[g + tid] = si;
    so_a[g + tid] = so;
    siS[tid] = si; soS[tid] = so;
  }
  __syncthreads();
  float sq = 0.f, sk = 0.f;
#pragma unroll
  for (int li = 0; li < 4; ++li) {
    const int l = w * 4 + li;
    sq += qS[l][lane] * siS[l];
    sk += kS[l][lane] * soS[l];
  }
  aS[w][lane] = sq; bS[w][lane] = sk;
  __syncthreads();
  if (tid < 64) {
    float s1 = 0.f, s2 = 0.f;
#pragma unroll
    for (int ww = 0; ww < 16; ++ww) { s1 += aS[ww][tid]; s2 += bS[ww][tid]; }
    sumQSI[bc * DH_ + tid] = s1;
    sumKSO[bc * DH_ + tid] = s2;
  }
}

// ---------------------------------------------------------------------------
// Flow phase 2: 1024 thr = 16 waves, 4 d-columns per wave.
// ---------------------------------------------------------------------------
__global__ __launch_bounds__(1024) void flow_phase2_k(const unsigned short* __restrict__ Qb,
                                                      const unsigned short* __restrict__ Kb,
                                                      const float* __restrict__ sumQSI,
                                                      const float* __restrict__ sumKSO,
                                                      const float* __restrict__ si_a,
                                                      const float* __restrict__ so_a,
                                                      float* __restrict__ salloc,
                                                      float* __restrict__ e_a,
                                                      float* __restrict__ sumE) {
  const int bc = blockIdx.x, bh = bc >> 4, c = bc & (NC_ - 1);
  const int g = bc * CT_;
  const int tid = threadIdx.x, lane = tid & 63, w = tid >> 6;
  __shared__ float qS[64][65], kS[64][65];
  __shared__ float pqS[64], pkS[64];
  __shared__ float aS[16][64], bS[16][64];
  if (tid < 512) {
    const int row = tid >> 3, d0 = (tid & 7) << 3;
    const bf16x8 qv = *(const bf16x8*)&Qb[(size_t)g * DH_ + tid * 8];
    const bf16x8 kv = *(const bf16x8*)&Kb[(size_t)g * DH_ + tid * 8];
#pragma unroll
    for (int j = 0; j < 8; ++j) {
      qS[row][d0 + j] = bf2f((unsigned short)qv[j]);
      kS[row][d0 + j] = bf2f((unsigned short)kv[j]);
    }
  } else if (tid < 576) {
    const int d = tid - 512;
    float pq = 0.f, pk = 0.f;
    for (int cc = 0; cc < c; ++cc) {
      pq += sumQSI[(bh * NC_ + cc) * DH_ + d];
      pk += sumKSO[(bh * NC_ + cc) * DH_ + d];
    }
    pqS[d] = pq; pkS[d] = pk;
  }
  __syncthreads();
  const float si = si_a[g + lane];
  const float so = so_a[g + lane];
  float c1p = 0.f, c2p = 0.f;
#pragma unroll
  for (int dd = 0; dd < 4; ++dd) {
    const int d = w * 4 + dd;
    const float qv = qS[lane][d];
    const float kv = kS[lane][d];
    float ckso = kv * so, cqsi = qv * si;
#pragma unroll
    for (int off = 1; off < 64; off <<= 1) {
      const float t1 = __shfl_up(ckso, off);
      const float t2 = __shfl_up(cqsi, off);
      ckso += (lane >= off) ? t1 : 0.f;
      cqsi += (lane >= off) ? t2 : 0.f;
    }
    ckso += pkS[d];
    cqsi += pqS[d];
    c1p += (qv + EPSF) * (ckso + EPSF);
    c2p += (kv + EPSF) * (cqsi + EPSF);
  }
  aS[w][lane] = c1p; bS[w][lane] = c2p;
  __syncthreads();
  if (tid < 64) {
    float c1 = 0.f, c2 = 0.f;
#pragma unroll
    for (int ww = 0; ww < 16; ++ww) { c1 += aS[ww][tid]; c2 += bS[ww][tid]; }
    const float normal = (float)(c * CT_ + tid + 1);
    const float cs_sink = c1 / normal;
    salloc[g + tid] = 1.0f / (1.0f + expf(-cs_sink));
    float cs_src = c2 / normal;
    cs_src = fminf(1.0f, fmaxf(-1.0f, cs_src));
    const float e = expf(cs_src);
    e_a[g + tid] = e;
    float tot = e;
#pragma unroll
    for (int off = 32; off; off >>= 1) tot += __shfl_xor(tot, off);
    if (tid == 0) sumE[bc] = tot;
  }
}

// ---------------------------------------------------------------------------
// Fused: source_competition + MFMA chunk-KV (k^T @ v'), 512 thr = 8 waves.
// Each wave computes a 16x32 sub-tile (4 MFMA); staging split over 8 waves.
// ---------------------------------------------------------------------------
__global__ __launch_bounds__(512) void flow_ckv_k(const unsigned short* __restrict__ K16,
                                                  const unsigned short* __restrict__ V16,
                                                  const float* __restrict__ e_a,
                                                  const float* __restrict__ sumE,
                                                  float* __restrict__ comp,
                                                  float* __restrict__ KV) {
  const int bc = blockIdx.x, bh = bc >> 4, c = bc & (NC_ - 1);
  const int g = bc * CT_;
  const int tid = threadIdx.x;
  __shared__ float compS[CT_];
  __shared__ __align__(16) unsigned short kT16[64 * 64];  // [d][l]
  __shared__ __align__(16) unsigned short vT16[64 * 64];  // [m][l] = v'[l][m]
  if (tid < 64) {
    const int lane = tid;
    const float e = e_a[g + lane];
    float se = (lane < c) ? sumE[bh * NC_ + lane] : 0.f;
#pragma unroll
    for (int off = 32; off; off >>= 1) se += __shfl_xor(se, off);
    float s = e;
#pragma unroll
    for (int off = 1; off < 64; off <<= 1) {
      const float t = __shfl_up(s, off);
      s += (lane >= off) ? t : 0.f;
    }
    const float cf = e / (se + s) * (float)(c * CT_ + lane + 1);
    compS[lane] = cf;
    comp[g + lane] = cf;
  }
  __syncthreads();
  {
    const int i8 = tid;  // [0,512): one bf16x8 pair per thread
    const int l = i8 >> 3, d0 = (i8 & 7) << 3;
    const bf16x8 kv = *(const bf16x8*)&K16[(size_t)g * DH_ + i8 * 8];
    const bf16x8 vv = *(const bf16x8*)&V16[(size_t)g * DH_ + i8 * 8];
    const float cl = compS[l];
#pragma unroll
    for (int j = 0; j < 8; ++j) {
      kT16[sw(d0 + j, l)] = (unsigned short)kv[j];
      vT16[sw(d0 + j, l)] = f2bf(bf2f((unsigned short)vv[j]) * cl);
    }
  }
  __syncthreads();
  const int lane = tid & 63, w = tid >> 6;        // w in [0,8)
  const int wr2 = w >> 1, wc2 = w & 1;            // 4x2 wave grid
  const int fr = lane & 15, fk = (lane >> 4) << 3;
  f32x4 acc[2] = {{0.f, 0.f, 0.f, 0.f}, {0.f, 0.f, 0.f, 0.f}};
  const bf16x8 a0 = *(const bf16x8*)&kT16[sw(wr2 * 16 + fr, fk)];
  const bf16x8 a1 = *(const bf16x8*)&kT16[sw(wr2 * 16 + fr, fk + 32)];
#pragma unroll
  for (int cb = 0; cb < 2; ++cb) {
    const int bcol = wc2 * 32 + cb * 16 + fr;
    const bf16x8 b0 = *(const bf16x8*)&vT16[sw(bcol, fk)];
    const bf16x8 b1 = *(const bf16x8*)&vT16[sw(bcol, fk + 32)];
    acc[cb] = __builtin_amdgcn_mfma_f32_16x16x32_bf16(a0, b0, acc[cb], 0, 0, 0);
    acc[cb] = __builtin_amdgcn_mfma_f32_16x16x32_bf16(a1, b1, acc[cb], 0, 0, 0);
  }
  float* outp = KV + (size_t)bc * DH_ * DH_;
#pragma unroll
  for (int r = 0; r < 4; ++r) {
    const int d = wr2 * 16 + (lane >> 4) * 4 + r;
#pragma unroll
    for (int cb = 0; cb < 2; ++cb)
      outp[d * DH_ + wc2 * 32 + cb * 16 + fr] = acc[cb][r];
  }
}

// ---------------------------------------------------------------------------
// MFMA attention, 512 thr = 8 waves: waves 0-3 = X-path (qp@KVp, then S@v'),
// waves 4-7 = S-path (qp@k^T -> masked S16), running concurrently. Inline KV
// prefix (unrolled masked sum over raw chunk KVs, L2-resident).
// ---------------------------------------------------------------------------
__global__ __launch_bounds__(512) void attn_k(const unsigned short* __restrict__ Q16,
                                              const unsigned short* __restrict__ K16,
                                              const unsigned short* __restrict__ V16,
                                              const float* __restrict__ KVraw,
                                              const float* __restrict__ qscale,
                                              const float* __restrict__ salloc,
                                              const float* __restrict__ comp,
                                              unsigned short* __restrict__ X) {
  const int bc = blockIdx.x;
  const int bh = bc >> 4, c = bc & (NC_ - 1);
  const int bb = bh >> 3, hh = bh & (H_ - 1);
  const int g = bc * CT_;
  __shared__ __align__(16) unsigned short qp16[64 * 64];  // [l][d]
  __shared__ __align__(16) unsigned short k16[64 * 64];   // [j][d]
  __shared__ __align__(16) unsigned short vT16[64 * 64];  // [m][j] = v'[j][m]
  __shared__ __align__(16) unsigned short kvT16[64 * 64]; // [m][d] = KVp[d][m]
  __shared__ __align__(16) unsigned short S16[64 * 64];   // [l][j] masked scores
  const int tid = threadIdx.x;
  {
    const int i8 = tid;  // [0,512)
    const int r = i8 >> 3, d0 = (i8 & 7) << 3;
    const bf16x8 qv = *(const bf16x8*)&Q16[(size_t)g * DH_ + i8 * 8];
    const bf16x8 kv = *(const bf16x8*)&K16[(size_t)g * DH_ + i8 * 8];
    const bf16x8 vv = *(const bf16x8*)&V16[(size_t)g * DH_ + i8 * 8];
    const float qs = qscale[g + r];
    const float cl = comp[g + r];
    bf16x8 pq;
#pragma unroll
    for (int j = 0; j < 8; ++j) pq[j] = (short)f2bf(bf2f((unsigned short)qv[j]) * qs);
    *(bf16x8*)&qp16[sw(r, d0)] = pq;
    *(bf16x8*)&k16[sw(r, d0)] = kv;
#pragma unroll
    for (int j = 0; j < 8; ++j)
      vT16[sw(d0 + j, r)] = f2bf(bf2f((unsigned short)vv[j]) * cl);
  }
  // kvT = transposed exclusive prefix: unrolled masked sum over raw chunk KVs
  {
    const float* kvbh = KVraw + (size_t)bh * NC_ * DH_ * DH_;
#pragma unroll
    for (int it = 0; it < 2; ++it) {
      const int i4 = it * 512 + tid;  // DH*DH/4 = 1024
      const int d = i4 >> 4, mg = (i4 & 15) << 2;
      float s0 = 0.f, s1 = 0.f, s2 = 0.f, s3 = 0.f;
#pragma unroll
      for (int cc = 0; cc < NC_; ++cc) {
        const float4 t = *(const float4*)&kvbh[(size_t)cc * (DH_ * DH_) + d * DH_ + mg];
        const float msk = (cc < c) ? 1.f : 0.f;
        s0 += t.x * msk; s1 += t.y * msk; s2 += t.z * msk; s3 += t.w * msk;
      }
      kvT16[sw(mg + 0, d)] = f2bf(s0);
      kvT16[sw(mg + 1, d)] = f2bf(s1);
      kvT16[sw(mg + 2, d)] = f2bf(s2);
      kvT16[sw(mg + 3, d)] = f2bf(s3);
    }
  }
  __syncthreads();

  const int lane = tid & 63, w = tid >> 6;   // w in [0,8)
  const int fr = lane & 15, fk = (lane >> 4) << 3;
  const int wS = (w >= 4) ? (w - 4) : w;     // row-group within [0,4)
  const int arow = wS * 16 + fr;
  const bf16x8 aq0 = *(const bf16x8*)&qp16[sw(arow, fk)];
  const bf16x8 aq1 = *(const bf16x8*)&qp16[sw(arow, fk + 32)];

  f32x4 accX[4] = {{0.f, 0.f, 0.f, 0.f}, {0.f, 0.f, 0.f, 0.f},
                   {0.f, 0.f, 0.f, 0.f}, {0.f, 0.f, 0.f, 0.f}};
  if (w < 4) {
    // X-path: qp @ KVp
#pragma unroll
    for (int cb = 0; cb < 4; ++cb) {
      const int bcol = cb * 16 + fr;
      const bf16x8 bv0 = *(const bf16x8*)&kvT16[sw(bcol, fk)];
      const bf16x8 bv1 = *(const bf16x8*)&kvT16[sw(bcol, fk + 32)];
      accX[cb] = __builtin_amdgcn_mfma_f32_16x16x32_bf16(aq0, bv0, accX[cb], 0, 0, 0);
      accX[cb] = __builtin_amdgcn_mfma_f32_16x16x32_bf16(aq1, bv1, accX[cb], 0, 0, 0);
    }
  } else {
    // S-path: scores qp @ k^T, masked bf16 writeback
    f32x4 accS[4] = {{0.f, 0.f, 0.f, 0.f}, {0.f, 0.f, 0.f, 0.f},
                     {0.f, 0.f, 0.f, 0.f}, {0.f, 0.f, 0.f, 0.f}};
#pragma unroll
    for (int cb = 0; cb < 4; ++cb) {
      const int bcol = cb * 16 + fr;
      const bf16x8 bk0 = *(const bf16x8*)&k16[sw(bcol, fk)];
      const bf16x8 bk1 = *(const bf16x8*)&k16[sw(bcol, fk + 32)];
      accS[cb] = __builtin_amdgcn_mfma_f32_16x16x32_bf16(aq0, bk0, accS[cb], 0, 0, 0);
      accS[cb] = __builtin_amdgcn_mfma_f32_16x16x32_bf16(aq1, bk1, accS[cb], 0, 0, 0);
    }
#pragma unroll
    for (int cb = 0; cb < 4; ++cb) {
#pragma unroll
      for (int r = 0; r < 4; ++r) {
        const int l = wS * 16 + (lane >> 4) * 4 + r;
        const int j = cb * 16 + fr;
        S16[sw(l, j)] = (j <= l) ? f2bf(accS[cb][r]) : (unsigned short)0;
      }
    }
  }
  __syncthreads();
  if (w < 4) {
    // X-path continued: + S @ v', epilogue
    const bf16x8 as0 = *(const bf16x8*)&S16[sw(arow, fk)];
    const bf16x8 as1 = *(const bf16x8*)&S16[sw(arow, fk + 32)];
#pragma unroll
    for (int cb = 0; cb < 4; ++cb) {
      const int bcol = cb * 16 + fr;
      const bf16x8 bv0 = *(const bf16x8*)&vT16[sw(bcol, fk)];
      const bf16x8 bv1 = *(const bf16x8*)&vT16[sw(bcol, fk + 32)];
      accX[cb] = __builtin_amdgcn_mfma_f32_16x16x32_bf16(as0, bv0, accX[cb], 0, 0, 0);
      accX[cb] = __builtin_amdgcn_mfma_f32_16x16x32_bf16(as1, bv1, accX[cb], 0, 0, 0);
    }
#pragma unroll
    for (int r = 0; r < 4; ++r) {
      const int l = wS * 16 + (lane >> 4) * 4 + r;
      const float sal = salloc[g + l];
      const size_t rowbase = ((size_t)(bb * L_ + c * CT_ + l)) * D_ + hh * DH_;
#pragma unroll
      for (int cb = 0; cb < 4; ++cb) {
        const int m = cb * 16 + fr;
        X[rowbase + m] = f2bf(accX[cb][r] * sal);
      }
    }
  }
}

// ---------------------------------------------------------------------------
// Output GEMM: d_out = X(bf16) @ Wo + bo. 64x64 tile, BK=64, 256 blocks.
// ---------------------------------------------------------------------------
__global__ __launch_bounds__(256) void gemm_out_k(const unsigned short* __restrict__ A,
                                                  const float* __restrict__ W,
                                                  const float* __restrict__ bias,
                                                  float* __restrict__ out) {
  __shared__ __align__(16) short Als[64 * 72];
  __shared__ __align__(16) short Bls[64 * 72];
  const int tid = threadIdx.x;
  const int m0 = blockIdx.x * 64, n0 = blockIdx.y * 64;
  const int arow = tid >> 2, ak0 = (tid & 3) << 4;   // 16 bf16, contiguous
  const int bcol = tid & 63, bk0 = (tid >> 6) << 4;  // 16 k-strided floats
  const int lane = tid & 63, wid = tid >> 6;
  const int wr = wid >> 1, wc = wid & 1;
  const int lrow = lane & 15, lk = (lane >> 4) << 3;

  f32x4 acc[2][2] = {{{0.f, 0.f, 0.f, 0.f}, {0.f, 0.f, 0.f, 0.f}},
                     {{0.f, 0.f, 0.f, 0.f}, {0.f, 0.f, 0.f, 0.f}}};
  bf16x8 pa0, pa1;
  float rb[16];
  auto loadAB = [&](int kt) {
    pa0 = *(const bf16x8*)&A[(size_t)(m0 + arow) * D_ + kt + ak0];
    pa1 = *(const bf16x8*)&A[(size_t)(m0 + arow) * D_ + kt + ak0 + 8];
    const float* gw = &W[(size_t)(kt + bk0) * D_ + n0 + bcol];
#pragma unroll
    for (int j = 0; j < 16; ++j) rb[j] = gw[(size_t)j * D_];
  };
  auto writeLDS = [&]() {
    bf16x8 pb0, pb1;
#pragma unroll
    for (int j = 0; j < 8; ++j) {
      pb0[j] = (short)f2bf(rb[j]);
      pb1[j] = (short)f2bf(rb[j + 8]);
    }
    *(bf16x8*)&Als[arow * 72 + ak0] = pa0;
    *(bf16x8*)&Als[arow * 72 + ak0 + 8] = pa1;
    *(bf16x8*)&Bls[bcol * 72 + bk0] = pb0;
    *(bf16x8*)&Bls[bcol * 72 + bk0 + 8] = pb1;
  };
  auto compute = [&]() {
#pragma unroll
    for (int ks = 0; ks < 2; ++ks) {
      const int ko = ks * 32 + lk;
      bf16x8 a0 = *(const bf16x8*)&Als[(wr * 32 + lrow) * 72 + ko];
      bf16x8 a1 = *(const bf16x8*)&Als[(wr * 32 + 16 + lrow) * 72 + ko];
      bf16x8 b0 = *(const bf16x8*)&Bls[(wc * 32 + lrow) * 72 + ko];
      bf16x8 b1 = *(const bf16x8*)&Bls[(wc * 32 + 16 + lrow) * 72 + ko];
      acc[0][0] = __builtin_amdgcn_mfma_f32_16x16x32_bf16(a0, b0, acc[0][0], 0, 0, 0);
      acc[0][1] = __builtin_amdgcn_mfma_f32_16x16x32_bf16(a0, b1, acc[0][1], 0, 0, 0);
      acc[1][0] = __builtin_amdgcn_mfma_f32_16x16x32_bf16(a1, b0, acc[1][0], 0, 0, 0);
      acc[1][1] = __builtin_amdgcn_mfma_f32_16x16x32_bf16(a1, b1, acc[1][1], 0, 0, 0);
    }
  };

  loadAB(0);
  writeLDS();
  for (int kt = 64; kt < D_; kt += 64) {
    loadAB(kt);
    __syncthreads();
    compute();
    __syncthreads();
    writeLDS();
  }
  __syncthreads();
  compute();

#pragma unroll
  for (int j = 0; j < 2; ++j) {
    const int col = n0 + wc * 32 + j * 16 + lrow;
    const float bv4 = bias[col];
#pragma unroll
    for (int i = 0; i < 2; ++i) {
#pragma unroll
      for (int r = 0; r < 4; ++r) {
        const int row = m0 + wr * 32 + i * 16 + (lane >> 4) * 4 + r;
        out[(size_t)row * D_ + col] = acc[i][j][r] + bv4;
      }
    }
  }
}

// ---------------------------------------------------------------------------
extern "C" void kernel_launch(void* const* d_in, const int* in_sizes, int n_in,
                              void* d_out, int out_size, void* d_ws, size_t ws_size,
                              hipStream_t stream) {
  (void)in_sizes; (void)n_in; (void)out_size; (void)ws_size;
  const float* queries = (const float*)d_in[0];
  const float* keys    = (const float*)d_in[1];
  const float* values  = (const float*)d_in[2];
  const float* Wq = (const float*)d_in[3];
  const float* bq = (const float*)d_in[4];
  const float* Wk = (const float*)d_in[5];
  const float* bk = (const float*)d_in[6];
  const float* Wv = (const float*)d_in[7];
  const float* bv = (const float*)d_in[8];
  const float* Wo = (const float*)d_in[9];
  const float* bo = (const float*)d_in[10];

  const size_t seg = (size_t)BH_ * L_ * DH_;  // 1,048,576 elements
  unsigned short* Qb = (unsigned short*)d_ws;          // bf16 [BH,L,Dh]
  unsigned short* Kb = Qb + seg;
  unsigned short* Vb = Kb + seg;
  float* KVb = (float*)(Vb + seg);                      // [BH, NC, 64, 64] raw
  float* p   = KVb + (size_t)BH_ * NC_ * DH_ * DH_;
  float* qscale = p; p += BH_ * L_;
  float* salloc = p; p += BH_ * L_;
  float* comp   = p; p += BH_ * L_;
  float* si_a   = p; p += BH_ * L_;
  float* so_a   = p; p += BH_ * L_;
  float* e_a    = p; p += BH_ * L_;
  float* sumQ   = p; p += BH_ * NC_ * DH_;
  float* sumK   = p; p += BH_ * NC_ * DH_;
  float* sumQSI = p; p += BH_ * NC_ * DH_;
  float* sumKSO = p; p += BH_ * NC_ * DH_;
  float* sumE   = p; p += BH_ * NC_;
  unsigned short* Xb16 = (unsigned short*)p;            // [BL, D] bf16

  proj3_k<<<dim3(BL_ / 64, D_ / 64, 3), 256, 0, stream>>>(
      queries, keys, values, Wq, bq, Wk, bk, Wv, bv, Qb, Kb, Vb, sumQ, sumK);
  flow_phase1_k<<<BH_ * NC_, 1024, 0, stream>>>(Qb, Kb, sumQ, sumK,
                                                qscale, si_a, so_a, sumQSI, sumKSO);
  flow_phase2_k<<<BH_ * NC_, 1024, 0, stream>>>(Qb, Kb, sumQSI, sumKSO, si_a, so_a,
                                                salloc, e_a, sumE);
  flow_ckv_k<<<BH_ * NC_, 512, 0, stream>>>(Kb, Vb, e_a, sumE, comp, KVb);
  attn_k<<<BH_ * NC_, 512, 0, stream>>>(Qb, Kb, Vb, KVb, qscale, salloc, comp, Xb16);
  gemm_out_k<<<dim3(BL_ / 64, D_ / 64), 256, 0, stream>>>(Xb16, Wo, bo, (float*)d_out);
}

// Round 14
// 55.727 us; speedup vs baseline: 1.1728x; 1.0124x over previous
//
#include <hip/hip_runtime.h>
#include <math.h>

#define EPSF 1e-6f

constexpr int B_  = 2;
constexpr int L_  = 1024;
constexpr int D_  = 512;
constexpr int H_  = 8;
constexpr int DH_ = 64;
constexpr int BL_ = B_ * L_;   // 2048
constexpr int BH_ = B_ * H_;   // 16
constexpr int CT_ = 64;        // chunk length
constexpr int NC_ = L_ / CT_;  // 16 chunks

typedef __attribute__((ext_vector_type(8))) short bf16x8;
typedef __attribute__((ext_vector_type(4))) float f32x4;

__device__ __forceinline__ unsigned short f2bf(float f) {
  union { float f; unsigned int u; } v; v.f = f;
  const unsigned int u = v.u;
  return (unsigned short)((u + 0x7FFFu + ((u >> 16) & 1u)) >> 16);  // RNE
}
__device__ __forceinline__ float bf2f(unsigned short u) {
  union { unsigned int u; float f; } v; v.u = ((unsigned int)u) << 16;
  return v.f;
}

// Swizzled ushort index for a [64][64] bf16 LDS tile: conflict-free b128 reads.
__device__ __forceinline__ int sw(int row, int col) {
  return row * 64 + (col ^ ((row & 7) << 3));
}

// ---------------------------------------------------------------------------
// Fused projection GEMMs, 64x64 tile, BK=64, 768 blocks x 512 thr = 8 waves
// (24 waves/CU). Wave = 16x32 output (2 MFMA/K-step). out = sigmoid?(A@W+b)
// stored BF16 permuted to [B,H,L,Dh]; z<2 also writes per-(chunk,head)
// column sums of ROUNDED values.
// ---------------------------------------------------------------------------
__global__ __launch_bounds__(512) void proj3_k(const float* __restrict__ Qin,
                                               const float* __restrict__ Kin,
                                               const float* __restrict__ Vin,
                                               const float* __restrict__ Wq,
                                               const float* __restrict__ bq,
                                               const float* __restrict__ Wk,
                                               const float* __restrict__ bk,
                                               const float* __restrict__ Wv,
                                               const float* __restrict__ bv,
                                               unsigned short* __restrict__ Qb,
                                               unsigned short* __restrict__ Kb,
                                               unsigned short* __restrict__ Vb,
                                               float* __restrict__ sumQ,
                                               float* __restrict__ sumK) {
  const int z = blockIdx.z;
  const float* A    = (z == 0) ? Qin : (z == 1) ? Kin : Vin;
  const float* W    = (z == 0) ? Wq  : (z == 1) ? Wk  : Wv;
  const float* bias = (z == 0) ? bq  : (z == 1) ? bk  : bv;
  unsigned short* out = (z == 0) ? Qb : (z == 1) ? Kb : Vb;
  float* csum       = (z == 0) ? sumQ : (z == 1) ? sumK : nullptr;
  const bool sig = (z < 2);

  __shared__ __align__(16) short Als[64 * 72];  // [row][k0..64], pad 72
  __shared__ __align__(16) short Bls[64 * 72];  // [col][k0..64]
  const int tid = threadIdx.x;
  const int m0 = blockIdx.x * 64, n0 = blockIdx.y * 64;
  const int arow = tid >> 3, ak0 = (tid & 7) << 3;  // 8 k-contig per thread
  const int bcol = tid & 63, bk0 = (tid >> 6) << 3; // 8 k-strided per thread
  const int lane = tid & 63, w = tid >> 6;          // w in [0,8)
  const int wr2 = w >> 1, wc2 = w & 1;              // 4x2 wave grid
  const int fr = lane & 15, lk = (lane >> 4) << 3;

  f32x4 acc[2] = {{0.f, 0.f, 0.f, 0.f}, {0.f, 0.f, 0.f, 0.f}};
  float ra[8], rb[8];

  auto loadAB = [&](int kt) {
    const float4 f0 = *(const float4*)&A[(size_t)(m0 + arow) * D_ + kt + ak0];
    const float4 f1 = *(const float4*)&A[(size_t)(m0 + arow) * D_ + kt + ak0 + 4];
    ra[0] = f0.x; ra[1] = f0.y; ra[2] = f0.z; ra[3] = f0.w;
    ra[4] = f1.x; ra[5] = f1.y; ra[6] = f1.z; ra[7] = f1.w;
    const float* gw = &W[(size_t)(kt + bk0) * D_ + n0 + bcol];
#pragma unroll
    for (int j = 0; j < 8; ++j) rb[j] = gw[(size_t)j * D_];
  };
  auto writeLDS = [&]() {
    bf16x8 pa, pb;
#pragma unroll
    for (int j = 0; j < 8; ++j) {
      pa[j] = (short)f2bf(ra[j]);
      pb[j] = (short)f2bf(rb[j]);
    }
    *(bf16x8*)&Als[arow * 72 + ak0] = pa;
    *(bf16x8*)&Bls[bcol * 72 + bk0] = pb;
  };
  auto compute = [&]() {
#pragma unroll
    for (int ks = 0; ks < 2; ++ks) {
      const int ko = ks * 32 + lk;
      bf16x8 a0 = *(const bf16x8*)&Als[(wr2 * 16 + fr) * 72 + ko];
      bf16x8 b0 = *(const bf16x8*)&Bls[(wc2 * 32 + fr) * 72 + ko];
      bf16x8 b1 = *(const bf16x8*)&Bls[(wc2 * 32 + 16 + fr) * 72 + ko];
      acc[0] = __builtin_amdgcn_mfma_f32_16x16x32_bf16(a0, b0, acc[0], 0, 0, 0);
      acc[1] = __builtin_amdgcn_mfma_f32_16x16x32_bf16(a0, b1, acc[1], 0, 0, 0);
    }
  };

  loadAB(0);
  writeLDS();
  for (int kt = 64; kt < D_; kt += 64) {
    loadAB(kt);       // register prefetch of next K-tile
    __syncthreads();
    compute();
    __syncthreads();
    writeLDS();
  }
  __syncthreads();
  compute();

  const int b = m0 >> 10, h = n0 >> 6;
  float psum[2] = {0.f, 0.f};
#pragma unroll
  for (int cb = 0; cb < 2; ++cb) {
    const int col = n0 + wc2 * 32 + cb * 16 + fr;
    const float bv4 = bias[col];
    const int dh = col & 63;
#pragma unroll
    for (int r = 0; r < 4; ++r) {
      const int row = m0 + wr2 * 16 + (lane >> 4) * 4 + r;
      float x = acc[cb][r] + bv4;
      if (sig) x = 1.0f / (1.0f + expf(-x));
      const unsigned short ub = f2bf(x);
      const int l = row & (L_ - 1);
      out[(((size_t)(b * H_ + h)) * L_ + l) * DH_ + dh] = ub;
      psum[cb] += bf2f(ub);  // sum the ROUNDED value: exact decomposition
    }
  }
  if (csum) {
    float* sumS = (float*)Als;  // reuse LDS: [4][64] floats
#pragma unroll
    for (int cb = 0; cb < 2; ++cb) {
      psum[cb] += __shfl_xor(psum[cb], 16);
      psum[cb] += __shfl_xor(psum[cb], 32);
      if ((lane >> 4) == 0)
        sumS[wr2 * 64 + wc2 * 32 + cb * 16 + fr] = psum[cb];
    }
    __syncthreads();
    if (tid < 64) {
      const int c = (m0 & (L_ - 1)) >> 6;
      const int bc = (b * H_ + h) * NC_ + c;
      csum[bc * DH_ + tid] =
          sumS[tid] + sumS[64 + tid] + sumS[128 + tid] + sumS[192 + tid];
    }
  }
}

// ---------------------------------------------------------------------------
// Flow phase 1: 1024 thr = 16 waves, each scanning 4 d-columns.
// ---------------------------------------------------------------------------
__global__ __launch_bounds__(1024) void flow_phase1_k(const unsigned short* __restrict__ Qb,
                                                      const unsigned short* __restrict__ Kb,
                                                      const float* __restrict__ sumQ,
                                                      const float* __restrict__ sumK,
                                                      float* __restrict__ qscale,
                                                      float* __restrict__ si_a,
                                                      float* __restrict__ so_a,
                                                      float* __restrict__ sumQSI,
                                                      float* __restrict__ sumKSO) {
  const int bc = blockIdx.x, bh = bc >> 4, c = bc & (NC_ - 1);
  const int g = bc * CT_;
  const int tid = threadIdx.x, lane = tid & 63, w = tid >> 6;  // w in [0,16)
  __shared__ float qS[64][65], kS[64][65];
  __shared__ float pqS[64], pkS[64];
  __shared__ float aS[16][64], bS[16][64];
  __shared__ float siS[64], soS[64];
  if (tid < 512) {
    const int row = tid >> 3, d0 = (tid & 7) << 3;
    const bf16x8 qv = *(const bf16x8*)&Qb[(size_t)g * DH_ + tid * 8];
    const bf16x8 kv = *(const bf16x8*)&Kb[(size_t)g * DH_ + tid * 8];
#pragma unroll
    for (int j = 0; j < 8; ++j) {
      qS[row][d0 + j] = bf2f((unsigned short)qv[j]);
      kS[row][d0 + j] = bf2f((unsigned short)kv[j]);
    }
  } else if (tid < 576) {
    const int d = tid - 512;
    float pq = 0.f, pk = 0.f;
    for (int cc = 0; cc < c; ++cc) {
      pq += sumQ[(bh * NC_ + cc) * DH_ + d];
      pk += sumK[(bh * NC_ + cc) * DH_ + d];
    }
    pqS[d] = pq; pkS[d] = pk;
  }
  __syncthreads();
  float ap = 0.f, bp = 0.f;
#pragma unroll
  for (int dd = 0; dd < 4; ++dd) {
    const int d = w * 4 + dd;
    const float qv = qS[lane][d];
    const float kv = kS[lane][d];
    float ck = kv, cq = qv;
#pragma unroll
    for (int off = 1; off < 64; off <<= 1) {
      const float t1 = __shfl_up(ck, off);
      const float t2 = __shfl_up(cq, off);
      ck += (lane >= off) ? t1 : 0.f;
      cq += (lane >= off) ? t2 : 0.f;
    }
    ck += pkS[d];
    cq += pqS[d];
    ap += (qv + EPSF) * (ck + EPSF);
    bp += (kv + EPSF) * (cq + EPSF);
  }
  aS[w][lane] = ap; bS[w][lane] = bp;
  __syncthreads();
  if (tid < 64) {
    float a = 0.f, b = 0.f;
#pragma unroll
    for (int ww = 0; ww < 16; ++ww) { a += aS[ww][tid]; b += bS[ww][tid]; }
    const float normal = (float)(c * CT_ + tid + 1);
    const float si = normal / a, so = normal / b;
    qscale[g + tid] = 1.0f / a;
    si_a[g + tid] = si;
    so_a[g + tid] = so;
    siS[tid] = si; soS[tid] = so;
  }
  __syncthreads();
  float sq = 0.f, sk = 0.f;
#pragma unroll
  for (int li = 0; li < 4; ++li) {
    const int l = w * 4 + li;
    sq += qS[l][lane] * siS[l];
    sk += kS[l][lane] * soS[l];
  }
  aS[w][lane] = sq; bS[w][lane] = sk;
  __syncthreads();
  if (tid < 64) {
    float s1 = 0.f, s2 = 0.f;
#pragma unroll
    for (int ww = 0; ww < 16; ++ww) { s1 += aS[ww][tid]; s2 += bS[ww][tid]; }
    sumQSI[bc * DH_ + tid] = s1;
    sumKSO[bc * DH_ + tid] = s2;
  }
}

// ---------------------------------------------------------------------------
// Flow phase 2: 1024 thr = 16 waves, 4 d-columns per wave.
// ---------------------------------------------------------------------------
__global__ __launch_bounds__(1024) void flow_phase2_k(const unsigned short* __restrict__ Qb,
                                                      const unsigned short* __restrict__ Kb,
                                                      const float* __restrict__ sumQSI,
                                                      const float* __restrict__ sumKSO,
                                                      const float* __restrict__ si_a,
                                                      const float* __restrict__ so_a,
                                                      float* __restrict__ salloc,
                                                      float* __restrict__ e_a,
                                                      float* __restrict__ sumE) {
  const int bc = blockIdx.x, bh = bc >> 4, c = bc & (NC_ - 1);
  const int g = bc * CT_;
  const int tid = threadIdx.x, lane = tid & 63, w = tid >> 6;
  __shared__ float qS[64][65], kS[64][65];
  __shared__ float pqS[64], pkS[64];
  __shared__ float aS[16][64], bS[16][64];
  if (tid < 512) {
    const int row = tid >> 3, d0 = (tid & 7) << 3;
    const bf16x8 qv = *(const bf16x8*)&Qb[(size_t)g * DH_ + tid * 8];
    const bf16x8 kv = *(const bf16x8*)&Kb[(size_t)g * DH_ + tid * 8];
#pragma unroll
    for (int j = 0; j < 8; ++j) {
      qS[row][d0 + j] = bf2f((unsigned short)qv[j]);
      kS[row][d0 + j] = bf2f((unsigned short)kv[j]);
    }
  } else if (tid < 576) {
    const int d = tid - 512;
    float pq = 0.f, pk = 0.f;
    for (int cc = 0; cc < c; ++cc) {
      pq += sumQSI[(bh * NC_ + cc) * DH_ + d];
      pk += sumKSO[(bh * NC_ + cc) * DH_ + d];
    }
    pqS[d] = pq; pkS[d] = pk;
  }
  __syncthreads();
  const float si = si_a[g + lane];
  const float so = so_a[g + lane];
  float c1p = 0.f, c2p = 0.f;
#pragma unroll
  for (int dd = 0; dd < 4; ++dd) {
    const int d = w * 4 + dd;
    const float qv = qS[lane][d];
    const float kv = kS[lane][d];
    float ckso = kv * so, cqsi = qv * si;
#pragma unroll
    for (int off = 1; off < 64; off <<= 1) {
      const float t1 = __shfl_up(ckso, off);
      const float t2 = __shfl_up(cqsi, off);
      ckso += (lane >= off) ? t1 : 0.f;
      cqsi += (lane >= off) ? t2 : 0.f;
    }
    ckso += pkS[d];
    cqsi += pqS[d];
    c1p += (qv + EPSF) * (ckso + EPSF);
    c2p += (kv + EPSF) * (cqsi + EPSF);
  }
  aS[w][lane] = c1p; bS[w][lane] = c2p;
  __syncthreads();
  if (tid < 64) {
    float c1 = 0.f, c2 = 0.f;
#pragma unroll
    for (int ww = 0; ww < 16; ++ww) { c1 += aS[ww][tid]; c2 += bS[ww][tid]; }
    const float normal = (float)(c * CT_ + tid + 1);
    const float cs_sink = c1 / normal;
    salloc[g + tid] = 1.0f / (1.0f + expf(-cs_sink));
    float cs_src = c2 / normal;
    cs_src = fminf(1.0f, fmaxf(-1.0f, cs_src));
    const float e = expf(cs_src);
    e_a[g + tid] = e;
    float tot = e;
#pragma unroll
    for (int off = 32; off; off >>= 1) tot += __shfl_xor(tot, off);
    if (tid == 0) sumE[bc] = tot;
  }
}

// ---------------------------------------------------------------------------
// Fused: source_competition + MFMA chunk-KV (k^T @ v'), 512 thr = 8 waves.
// ---------------------------------------------------------------------------
__global__ __launch_bounds__(512) void flow_ckv_k(const unsigned short* __restrict__ K16,
                                                  const unsigned short* __restrict__ V16,
                                                  const float* __restrict__ e_a,
                                                  const float* __restrict__ sumE,
                                                  float* __restrict__ comp,
                                                  float* __restrict__ KV) {
  const int bc = blockIdx.x, bh = bc >> 4, c = bc & (NC_ - 1);
  const int g = bc * CT_;
  const int tid = threadIdx.x;
  __shared__ float compS[CT_];
  __shared__ __align__(16) unsigned short kT16[64 * 64];  // [d][l]
  __shared__ __align__(16) unsigned short vT16[64 * 64];  // [m][l] = v'[l][m]
  if (tid < 64) {
    const int lane = tid;
    const float e = e_a[g + lane];
    float se = (lane < c) ? sumE[bh * NC_ + lane] : 0.f;
#pragma unroll
    for (int off = 32; off; off >>= 1) se += __shfl_xor(se, off);
    float s = e;
#pragma unroll
    for (int off = 1; off < 64; off <<= 1) {
      const float t = __shfl_up(s, off);
      s += (lane >= off) ? t : 0.f;
    }
    const float cf = e / (se + s) * (float)(c * CT_ + lane + 1);
    compS[lane] = cf;
    comp[g + lane] = cf;
  }
  __syncthreads();
  {
    const int i8 = tid;  // [0,512): one bf16x8 pair per thread
    const int l = i8 >> 3, d0 = (i8 & 7) << 3;
    const bf16x8 kv = *(const bf16x8*)&K16[(size_t)g * DH_ + i8 * 8];
    const bf16x8 vv = *(const bf16x8*)&V16[(size_t)g * DH_ + i8 * 8];
    const float cl = compS[l];
#pragma unroll
    for (int j = 0; j < 8; ++j) {
      kT16[sw(d0 + j, l)] = (unsigned short)kv[j];
      vT16[sw(d0 + j, l)] = f2bf(bf2f((unsigned short)vv[j]) * cl);
    }
  }
  __syncthreads();
  const int lane = tid & 63, w = tid >> 6;        // w in [0,8)
  const int wr2 = w >> 1, wc2 = w & 1;            // 4x2 wave grid
  const int fr = lane & 15, fk = (lane >> 4) << 3;
  f32x4 acc[2] = {{0.f, 0.f, 0.f, 0.f}, {0.f, 0.f, 0.f, 0.f}};
  const bf16x8 a0 = *(const bf16x8*)&kT16[sw(wr2 * 16 + fr, fk)];
  const bf16x8 a1 = *(const bf16x8*)&kT16[sw(wr2 * 16 + fr, fk + 32)];
#pragma unroll
  for (int cb = 0; cb < 2; ++cb) {
    const int bcol = wc2 * 32 + cb * 16 + fr;
    const bf16x8 b0 = *(const bf16x8*)&vT16[sw(bcol, fk)];
    const bf16x8 b1 = *(const bf16x8*)&vT16[sw(bcol, fk + 32)];
    acc[cb] = __builtin_amdgcn_mfma_f32_16x16x32_bf16(a0, b0, acc[cb], 0, 0, 0);
    acc[cb] = __builtin_amdgcn_mfma_f32_16x16x32_bf16(a1, b1, acc[cb], 0, 0, 0);
  }
  float* outp = KV + (size_t)bc * DH_ * DH_;
#pragma unroll
  for (int r = 0; r < 4; ++r) {
    const int d = wr2 * 16 + (lane >> 4) * 4 + r;
#pragma unroll
    for (int cb = 0; cb < 2; ++cb)
      outp[d * DH_ + wc2 * 32 + cb * 16 + fr] = acc[cb][r];
  }
}

// ---------------------------------------------------------------------------
// MFMA attention, 512 thr = 8 waves: waves 0-3 = X-path (qp@KVp, then S@v'),
// waves 4-7 = S-path (qp@k^T -> masked S16), running concurrently. Inline KV
// prefix (unrolled masked sum over raw chunk KVs, L2-resident).
// ---------------------------------------------------------------------------
__global__ __launch_bounds__(512) void attn_k(const unsigned short* __restrict__ Q16,
                                              const unsigned short* __restrict__ K16,
                                              const unsigned short* __restrict__ V16,
                                              const float* __restrict__ KVraw,
                                              const float* __restrict__ qscale,
                                              const float* __restrict__ salloc,
                                              const float* __restrict__ comp,
                                              unsigned short* __restrict__ X) {
  const int bc = blockIdx.x;
  const int bh = bc >> 4, c = bc & (NC_ - 1);
  const int bb = bh >> 3, hh = bh & (H_ - 1);
  const int g = bc * CT_;
  __shared__ __align__(16) unsigned short qp16[64 * 64];  // [l][d]
  __shared__ __align__(16) unsigned short k16[64 * 64];   // [j][d]
  __shared__ __align__(16) unsigned short vT16[64 * 64];  // [m][j] = v'[j][m]
  __shared__ __align__(16) unsigned short kvT16[64 * 64]; // [m][d] = KVp[d][m]
  __shared__ __align__(16) unsigned short S16[64 * 64];   // [l][j] masked scores
  const int tid = threadIdx.x;
  {
    const int i8 = tid;  // [0,512)
    const int r = i8 >> 3, d0 = (i8 & 7) << 3;
    const bf16x8 qv = *(const bf16x8*)&Q16[(size_t)g * DH_ + i8 * 8];
    const bf16x8 kv = *(const bf16x8*)&K16[(size_t)g * DH_ + i8 * 8];
    const bf16x8 vv = *(const bf16x8*)&V16[(size_t)g * DH_ + i8 * 8];
    const float qs = qscale[g + r];
    const float cl = comp[g + r];
    bf16x8 pq;
#pragma unroll
    for (int j = 0; j < 8; ++j) pq[j] = (short)f2bf(bf2f((unsigned short)qv[j]) * qs);
    *(bf16x8*)&qp16[sw(r, d0)] = pq;
    *(bf16x8*)&k16[sw(r, d0)] = kv;
#pragma unroll
    for (int j = 0; j < 8; ++j)
      vT16[sw(d0 + j, r)] = f2bf(bf2f((unsigned short)vv[j]) * cl);
  }
  // kvT = transposed exclusive prefix: unrolled masked sum over raw chunk KVs
  {
    const float* kvbh = KVraw + (size_t)bh * NC_ * DH_ * DH_;
#pragma unroll
    for (int it = 0; it < 2; ++it) {
      const int i4 = it * 512 + tid;  // DH*DH/4 = 1024
      const int d = i4 >> 4, mg = (i4 & 15) << 2;
      float s0 = 0.f, s1 = 0.f, s2 = 0.f, s3 = 0.f;
#pragma unroll
      for (int cc = 0; cc < NC_; ++cc) {
        const float4 t = *(const float4*)&kvbh[(size_t)cc * (DH_ * DH_) + d * DH_ + mg];
        const float msk = (cc < c) ? 1.f : 0.f;
        s0 += t.x * msk; s1 += t.y * msk; s2 += t.z * msk; s3 += t.w * msk;
      }
      kvT16[sw(mg + 0, d)] = f2bf(s0);
      kvT16[sw(mg + 1, d)] = f2bf(s1);
      kvT16[sw(mg + 2, d)] = f2bf(s2);
      kvT16[sw(mg + 3, d)] = f2bf(s3);
    }
  }
  __syncthreads();

  const int lane = tid & 63, w = tid >> 6;   // w in [0,8)
  const int fr = lane & 15, fk = (lane >> 4) << 3;
  const int wS = (w >= 4) ? (w - 4) : w;     // row-group within [0,4)
  const int arow = wS * 16 + fr;
  const bf16x8 aq0 = *(const bf16x8*)&qp16[sw(arow, fk)];
  const bf16x8 aq1 = *(const bf16x8*)&qp16[sw(arow, fk + 32)];

  f32x4 accX[4] = {{0.f, 0.f, 0.f, 0.f}, {0.f, 0.f, 0.f, 0.f},
                   {0.f, 0.f, 0.f, 0.f}, {0.f, 0.f, 0.f, 0.f}};
  if (w < 4) {
    // X-path: qp @ KVp
#pragma unroll
    for (int cb = 0; cb < 4; ++cb) {
      const int bcol = cb * 16 + fr;
      const bf16x8 bv0 = *(const bf16x8*)&kvT16[sw(bcol, fk)];
      const bf16x8 bv1 = *(const bf16x8*)&kvT16[sw(bcol, fk + 32)];
      accX[cb] = __builtin_amdgcn_mfma_f32_16x16x32_bf16(aq0, bv0, accX[cb], 0, 0, 0);
      accX[cb] = __builtin_amdgcn_mfma_f32_16x16x32_bf16(aq1, bv1, accX[cb], 0, 0, 0);
    }
  } else {
    // S-path: scores qp @ k^T, masked bf16 writeback
    f32x4 accS[4] = {{0.f, 0.f, 0.f, 0.f}, {0.f, 0.f, 0.f, 0.f},
                     {0.f, 0.f, 0.f, 0.f}, {0.f, 0.f, 0.f, 0.f}};
#pragma unroll
    for (int cb = 0; cb < 4; ++cb) {
      const int bcol = cb * 16 + fr;
      const bf16x8 bk0 = *(const bf16x8*)&k16[sw(bcol, fk)];
      const bf16x8 bk1 = *(const bf16x8*)&k16[sw(bcol, fk + 32)];
      accS[cb] = __builtin_amdgcn_mfma_f32_16x16x32_bf16(aq0, bk0, accS[cb], 0, 0, 0);
      accS[cb] = __builtin_amdgcn_mfma_f32_16x16x32_bf16(aq1, bk1, accS[cb], 0, 0, 0);
    }
#pragma unroll
    for (int cb = 0; cb < 4; ++cb) {
#pragma unroll
      for (int r = 0; r < 4; ++r) {
        const int l = wS * 16 + (lane >> 4) * 4 + r;
        const int j = cb * 16 + fr;
        S16[sw(l, j)] = (j <= l) ? f2bf(accS[cb][r]) : (unsigned short)0;
      }
    }
  }
  __syncthreads();
  if (w < 4) {
    // X-path continued: + S @ v', epilogue
    const bf16x8 as0 = *(const bf16x8*)&S16[sw(arow, fk)];
    const bf16x8 as1 = *(const bf16x8*)&S16[sw(arow, fk + 32)];
#pragma unroll
    for (int cb = 0; cb < 4; ++cb) {
      const int bcol = cb * 16 + fr;
      const bf16x8 bv0 = *(const bf16x8*)&vT16[sw(bcol, fk)];
      const bf16x8 bv1 = *(const bf16x8*)&vT16[sw(bcol, fk + 32)];
      accX[cb] = __builtin_amdgcn_mfma_f32_16x16x32_bf16(as0, bv0, accX[cb], 0, 0, 0);
      accX[cb] = __builtin_amdgcn_mfma_f32_16x16x32_bf16(as1, bv1, accX[cb], 0, 0, 0);
    }
#pragma unroll
    for (int r = 0; r < 4; ++r) {
      const int l = wS * 16 + (lane >> 4) * 4 + r;
      const float sal = salloc[g + l];
      const size_t rowbase = ((size_t)(bb * L_ + c * CT_ + l)) * D_ + hh * DH_;
#pragma unroll
      for (int cb = 0; cb < 4; ++cb) {
        const int m = cb * 16 + fr;
        X[rowbase + m] = f2bf(accX[cb][r] * sal);
      }
    }
  }
}

// ---------------------------------------------------------------------------
// Output GEMM: d_out = X(bf16) @ Wo + bo. 64x64 tile, BK=64, 256 blocks x
// 512 thr = 8 waves (wave = 16x32 output).
// ---------------------------------------------------------------------------
__global__ __launch_bounds__(512) void gemm_out_k(const unsigned short* __restrict__ A,
                                                  const float* __restrict__ W,
                                                  const float* __restrict__ bias,
                                                  float* __restrict__ out) {
  __shared__ __align__(16) short Als[64 * 72];
  __shared__ __align__(16) short Bls[64 * 72];
  const int tid = threadIdx.x;
  const int m0 = blockIdx.x * 64, n0 = blockIdx.y * 64;
  const int arow = tid >> 3, ak0 = (tid & 7) << 3;   // 8 bf16, contiguous
  const int bcol = tid & 63, bk0 = (tid >> 6) << 3;  // 8 k-strided floats
  const int lane = tid & 63, w = tid >> 6;           // w in [0,8)
  const int wr2 = w >> 1, wc2 = w & 1;               // 4x2 wave grid
  const int fr = lane & 15, lk = (lane >> 4) << 3;

  f32x4 acc[2] = {{0.f, 0.f, 0.f, 0.f}, {0.f, 0.f, 0.f, 0.f}};
  bf16x8 pa;
  float rb[8];
  auto loadAB = [&](int kt) {
    pa = *(const bf16x8*)&A[(size_t)(m0 + arow) * D_ + kt + ak0];
    const float* gw = &W[(size_t)(kt + bk0) * D_ + n0 + bcol];
#pragma unroll
    for (int j = 0; j < 8; ++j) rb[j] = gw[(size_t)j * D_];
  };
  auto writeLDS = [&]() {
    bf16x8 pb;
#pragma unroll
    for (int j = 0; j < 8; ++j) pb[j] = (short)f2bf(rb[j]);
    *(bf16x8*)&Als[arow * 72 + ak0] = pa;
    *(bf16x8*)&Bls[bcol * 72 + bk0] = pb;
  };
  auto compute = [&]() {
#pragma unroll
    for (int ks = 0; ks < 2; ++ks) {
      const int ko = ks * 32 + lk;
      bf16x8 a0 = *(const bf16x8*)&Als[(wr2 * 16 + fr) * 72 + ko];
      bf16x8 b0 = *(const bf16x8*)&Bls[(wc2 * 32 + fr) * 72 + ko];
      bf16x8 b1 = *(const bf16x8*)&Bls[(wc2 * 32 + 16 + fr) * 72 + ko];
      acc[0] = __builtin_amdgcn_mfma_f32_16x16x32_bf16(a0, b0, acc[0], 0, 0, 0);
      acc[1] = __builtin_amdgcn_mfma_f32_16x16x32_bf16(a0, b1, acc[1], 0, 0, 0);
    }
  };

  loadAB(0);
  writeLDS();
  for (int kt = 64; kt < D_; kt += 64) {
    loadAB(kt);
    __syncthreads();
    compute();
    __syncthreads();
    writeLDS();
  }
  __syncthreads();
  compute();

#pragma unroll
  for (int cb = 0; cb < 2; ++cb) {
    const int col = n0 + wc2 * 32 + cb * 16 + fr;
    const float bv4 = bias[col];
#pragma unroll
    for (int r = 0; r < 4; ++r) {
      const int row = m0 + wr2 * 16 + (lane >> 4) * 4 + r;
      out[(size_t)row * D_ + col] = acc[cb][r] + bv4;
    }
  }
}

// ---------------------------------------------------------------------------
extern "C" void kernel_launch(void* const* d_in, const int* in_sizes, int n_in,
                              void* d_out, int out_size, void* d_ws, size_t ws_size,
                              hipStream_t stream) {
  (void)in_sizes; (void)n_in; (void)out_size; (void)ws_size;
  const float* queries = (const float*)d_in[0];
  const float* keys    = (const float*)d_in[1];
  const float* values  = (const float*)d_in[2];
  const float* Wq = (const float*)d_in[3];
  const float* bq = (const float*)d_in[4];
  const float* Wk = (const float*)d_in[5];
  const float* bk = (const float*)d_in[6];
  const float* Wv = (const float*)d_in[7];
  const float* bv = (const float*)d_in[8];
  const float* Wo = (const float*)d_in[9];
  const float* bo = (const float*)d_in[10];

  const size_t seg = (size_t)BH_ * L_ * DH_;  // 1,048,576 elements
  unsigned short* Qb = (unsigned short*)d_ws;          // bf16 [BH,L,Dh]
  unsigned short* Kb = Qb + seg;
  unsigned short* Vb = Kb + seg;
  float* KVb = (float*)(Vb + seg);                      // [BH, NC, 64, 64] raw
  float* p   = KVb + (size_t)BH_ * NC_ * DH_ * DH_;
  float* qscale = p; p += BH_ * L_;
  float* salloc = p; p += BH_ * L_;
  float* comp   = p; p += BH_ * L_;
  float* si_a   = p; p += BH_ * L_;
  float* so_a   = p; p += BH_ * L_;
  float* e_a    = p; p += BH_ * L_;
  float* sumQ   = p; p += BH_ * NC_ * DH_;
  float* sumK   = p; p += BH_ * NC_ * DH_;
  float* sumQSI = p; p += BH_ * NC_ * DH_;
  float* sumKSO = p; p += BH_ * NC_ * DH_;
  float* sumE   = p; p += BH_ * NC_;
  unsigned short* Xb16 = (unsigned short*)p;            // [BL, D] bf16

  proj3_k<<<dim3(BL_ / 64, D_ / 64, 3), 512, 0, stream>>>(
      queries, keys, values, Wq, bq, Wk, bk, Wv, bv, Qb, Kb, Vb, sumQ, sumK);
  flow_phase1_k<<<BH_ * NC_, 1024, 0, stream>>>(Qb, Kb, sumQ, sumK,
                                                qscale, si_a, so_a, sumQSI, sumKSO);
  flow_phase2_k<<<BH_ * NC_, 1024, 0, stream>>>(Qb, Kb, sumQSI, sumKSO, si_a, so_a,
                                                salloc, e_a, sumE);
  flow_ckv_k<<<BH_ * NC_, 512, 0, stream>>>(Kb, Vb, e_a, sumE, comp, KVb);
  attn_k<<<BH_ * NC_, 512, 0, stream>>>(Qb, Kb, Vb, KVb, qscale, salloc, comp, Xb16);
  gemm_out_k<<<dim3(BL_ / 64, D_ / 64), 512, 0, stream>>>(Xb16, Wo, bo, (float*)d_out);
}